// Round 10
// baseline (465.089 us; speedup 1.0000x reference)
//
#include <hip/hip_runtime.h>
#include <math.h>

#define NS 300
#define NK 47
#define NHID 96
#define NFULL 48

typedef __attribute__((ext_vector_type(8))) short bf16x8;
typedef __attribute__((ext_vector_type(4))) float f32x4;
typedef __attribute__((ext_vector_type(4))) short s16x4;

__device__ __forceinline__ float sigmoidf(float x){ return 1.0f/(1.0f+expf(-x)); }
__device__ __forceinline__ short f2bf(float f){
    union { float f; unsigned u; } v; v.f = f;
    unsigned r = v.u + 0x7fffu + ((v.u >> 16) & 1u);
    return (short)(r >> 16);
}
__device__ __forceinline__ float bf2f(short s){
    union { unsigned u; float f; } v; v.u = ((unsigned)(unsigned short)s) << 16;
    return v.f;
}
__device__ __forceinline__ unsigned pk(short lo, short hi){
    return (unsigned)(unsigned short)lo | ((unsigned)(unsigned short)hi << 16);
}

// c-tensor layout (all c64 buffers): addr(z,y,g,x,j) = ((z*N+y)*8+g)*N*8 + x*8 + j
//   g = ci>>3 (0..7), j = ci&7.  A 16-lane x-slice at fixed g is 256B contiguous.
// Groups 6,7 hold zeros (written by init_c / cascade pad loop) — R4 semantics.
// AQ_Tb rows padded to 48 floats (192B, 16B-aligned) for vector loads.

// ---------------------------------------------------------------------------
// Kernel 1 (merged prologue): block 0 = AQT split-bf16 Gram47 + Newton-Schulz
// inverses (A47+dreg pad48, A18+0.01 pad32) + Bseq; blocks 1..41 = w1->bf16
// conversion; blocks 42..44 = w2/w3->bf16.
// ---------------------------------------------------------------------------
#define AQP 328
#define P47 72
#define P18 40
__global__ __launch_bounds__(256) void prep_small(const float* __restrict__ AQ,
                           const float* __restrict__ dreg_p,
                           float* __restrict__ Ainv18, short* __restrict__ Ainvbf,
                           short* __restrict__ Bseq,
                           const float* __restrict__ w1, short* __restrict__ w1bf,
                           const float* __restrict__ w2, const float* __restrict__ w3,
                           short* __restrict__ w2bf, short* __restrict__ w3bf){
    __shared__ __align__(16) char smem[93824];

    const int tid = threadIdx.x;
    const int blk = blockIdx.x;

    if (blk >= 1){
        if (blk <= 41){
            int idx = (blk - 1)*256 + tid;
            if (idx < 4*27*96){
                int o = idx % 96; int rest = idx / 96; int s = rest % 27; int i = rest / 27;
                const float* src = w1 + ((size_t)i*96 + o)*1269 + s;
                short* dst = w1bf + (size_t)idx*64;
                #pragma unroll
                for (int ci = 0; ci < 47; ++ci) dst[ci] = f2bf(src[ci*27]);
                #pragma unroll
                for (int ci = 47; ci < 64; ++ci) dst[ci] = 0;
            }
        } else {
            int idx = (blk - 42)*256 + tid;
            if (idx < 768){
                if (idx < 384){
                    const float* src = w2 + (size_t)idx*96;
                    short* dst = w2bf + (size_t)idx*96;
                    for (int k = 0; k < 96; ++k) dst[k] = f2bf(src[k]);
                } else {
                    int j = idx - 384;
                    int i = j / 96, o = j % 96;
                    short* dst = w3bf + (size_t)j*96;
                    if (o < 94){
                        const float* src = w3 + ((size_t)i*94 + o)*96;
                        for (int k = 0; k < 96; ++k) dst[k] = f2bf(src[k]);
                    } else {
                        for (int k = 0; k < 96; ++k) dst[k] = 0;
                    }
                }
            }
        }
        return;
    }

    short* AQh = (short*)smem;
    short* AQl = AQh + 48*AQP;
    float* Gf  = (float*)(smem + 62976);
    short* M47 = (short*)smem;
    short* M18 = (short*)(smem + 72960);
    float* rs47 = (float*)(smem + 93440);
    float* rs18 = rs47 + 48;
    float* shc  = rs18 + 32;

    const int lane = tid & 63;
    const int wv  = tid >> 6;
    const int l15 = lane & 15;
    const int lhi = lane >> 4;
    const float dreg = dreg_p[0];

    #pragma unroll 4
    for (int idx = tid; idx < 48*AQP; idx += 256){
        int k = idx / AQP, n = idx - k*AQP;
        float a = (k < 47 && n < 300) ? AQ[n*NK + k] : 0.f;
        short h = f2bf(a);
        short l = f2bf(a - bf2f(h));
        AQh[idx] = h; AQl[idx] = l;
        if (n < 320){
            int step = n >> 5, lh = (n >> 3) & 3, j = n & 7;
            int t = k >> 4, kl = k & 15;
            int base = ((step*3 + t)*2)*512 + (lh*16 + kl)*8 + j;
            Bseq[base]       = h;
            Bseq[base + 512] = l;
        }
    }
    __syncthreads();

    const int t0 = wv, t1 = wv + 4, t2 = wv + 8;
    f32x4 g0, g1, g2;
    {
        auto gram = [&](int t) -> f32x4 {
            int tt = (t < 9) ? t : t - 9;
            int k0 = (tt/3)*16, l0 = (tt%3)*16;
            f32x4 a = (f32x4){0.f,0.f,0.f,0.f};
            for (int ks = 0; ks < 10; ++ks){
                int off = ks*32 + lhi*8;
                bf16x8 ph = *(const bf16x8*)&AQh[(k0+l15)*AQP + off];
                bf16x8 pl = *(const bf16x8*)&AQl[(k0+l15)*AQP + off];
                bf16x8 qh = *(const bf16x8*)&AQh[(l0+l15)*AQP + off];
                bf16x8 ql = *(const bf16x8*)&AQl[(l0+l15)*AQP + off];
                a = __builtin_amdgcn_mfma_f32_16x16x32_bf16(ph, qh, a, 0,0,0);
                a = __builtin_amdgcn_mfma_f32_16x16x32_bf16(pl, qh, a, 0,0,0);
                a = __builtin_amdgcn_mfma_f32_16x16x32_bf16(ph, ql, a, 0,0,0);
            }
            return a;
        };
        g0 = gram(t0); g1 = gram(t1); g2 = gram(t2);
    }
    __syncthreads();

    for (int i = tid; i < 8*48*P47; i += 256) M47[i] = 0;
    for (int i = tid; i < 8*32*P18; i += 256) M18[i] = 0;
    {
        auto wrG = [&](int t, f32x4 a){
            if (t < 9){
                int k0 = (t/3)*16, l0 = (t%3)*16;
                #pragma unroll
                for (int r = 0; r < 4; ++r)
                    Gf[(k0 + lhi*4 + r)*52 + (l0 + l15)] = a[r];
            }
        };
        wrG(t0,g0); wrG(t1,g1); wrG(t2,g2);
    }
    __syncthreads();

    short* Ah  = M47;            short* Al  = M47 + 3456;
    short* Xah = M47 + 2*3456;   short* Xal = M47 + 3*3456;
    short* Xbh = M47 + 4*3456;   short* Xbl = M47 + 5*3456;
    short* Zh  = M47 + 6*3456;   short* Zl  = M47 + 7*3456;
    short* Bh8 = M18;            short* Bl8 = M18 + 1280;
    short* Xah8= M18 + 2*1280;   short* Xal8= M18 + 3*1280;
    short* Xbh8= M18 + 4*1280;   short* Xbl8= M18 + 5*1280;
    short* Zh8 = M18 + 6*1280;   short* Zl8 = M18 + 7*1280;

    {
        auto wrA = [&](int t, f32x4 a){
            if (t < 9){
                int k0 = (t/3)*16, l0 = (t%3)*16;
                #pragma unroll
                for (int r = 0; r < 4; ++r){
                    int k = k0 + lhi*4 + r, l = l0 + l15;
                    float v = (k < 47 && l < 47) ? a[r] + (k==l ? dreg : 0.f)
                                                 : ((k==l) ? 1.f : 0.f);
                    short h = f2bf(v);
                    Ah[k*P47 + l] = h;
                    Al[k*P47 + l] = f2bf(v - bf2f(h));
                }
            }
        };
        wrA(t0,g0); wrA(t1,g1); wrA(t2,g2);
    }
    if (tid < 48){
        float s = 1.f;
        if (tid < 47){
            s = dreg;
            for (int l = 0; l < 47; ++l) s += fabsf(Gf[tid*52 + l]);
        }
        rs47[tid] = s;
    }
    if (tid >= 64 && tid < 96){
        int r = tid - 64;
        float s = 1.f;
        if (r < 18){
            int gk = (r < 16) ? r : r + 29;
            s = 0.f;
            for (int l = 0; l < 18; ++l){
                int gl = (l < 16) ? l : l + 29;
                s += fabsf(Gf[gk*52 + gl] + ((l==r) ? 0.01f : 0.f));
            }
        }
        rs18[r] = s;
    }
    for (int e = tid; e < 32*32; e += 256){
        int k = e >> 5, l = e & 31;
        float v;
        if (k < 18 && l < 18){
            int gk = (k < 16) ? k : k + 29;
            int gl = (l < 16) ? l : l + 29;
            v = Gf[gk*52 + gl] + ((k==l) ? 0.01f : 0.f);
        } else v = (k==l) ? 1.f : 0.f;
        short h = f2bf(v);
        Bh8[k*P18 + l] = h;
        Bl8[k*P18 + l] = f2bf(v - bf2f(h));
    }
    __syncthreads();

    if (tid == 0){
        float m = 0.f;
        for (int i = 0; i < 48; ++i) m = fmaxf(m, rs47[i]);
        shc[0] = 1.f / m;
    }
    if (tid == 1){
        float m = 0.f;
        for (int i = 0; i < 32; ++i) m = fmaxf(m, rs18[i]);
        shc[1] = 1.f / m;
    }
    __syncthreads();

    if (tid < 48){
        float c = shc[0];
        short h = f2bf(c);
        Xah[tid*P47 + tid] = h;
        Xal[tid*P47 + tid] = f2bf(c - bf2f(h));
    } else if (tid >= 64 && tid < 96){
        int r = tid - 64;
        float c = shc[1];
        short h = f2bf(c);
        Xah8[r*P18 + r] = h;
        Xal8[r*P18 + r] = f2bf(c - bf2f(h));
    }
    __syncthreads();

    auto mmT = [&](int t, const short* Ph, const short* Pl,
                   const short* Qh, const short* Ql) -> f32x4 {
        int tt = (t < 9) ? t : t - 9;
        int k0 = (tt/3)*16, l0 = (tt%3)*16;
        f32x4 a = (f32x4){0.f,0.f,0.f,0.f};
        #pragma unroll
        for (int kk = 0; kk < 2; ++kk){
            int off = kk*32 + lhi*8;
            bf16x8 ph = *(const bf16x8*)&Ph[(k0+l15)*P47 + off];
            bf16x8 pl = *(const bf16x8*)&Pl[(k0+l15)*P47 + off];
            bf16x8 qh = *(const bf16x8*)&Qh[(l0+l15)*P47 + off];
            bf16x8 ql = *(const bf16x8*)&Ql[(l0+l15)*P47 + off];
            a = __builtin_amdgcn_mfma_f32_16x16x32_bf16(ph, qh, a, 0,0,0);
            a = __builtin_amdgcn_mfma_f32_16x16x32_bf16(pl, qh, a, 0,0,0);
            a = __builtin_amdgcn_mfma_f32_16x16x32_bf16(ph, ql, a, 0,0,0);
        }
        return a;
    };
    auto mm8 = [&](const short* Ph, const short* Pl,
                   const short* Qh, const short* Ql) -> f32x4 {
        int k0 = (wv >> 1)*16, l0 = (wv & 1)*16;
        int off = lhi*8;
        bf16x8 ph = *(const bf16x8*)&Ph[(k0+l15)*P18 + off];
        bf16x8 pl = *(const bf16x8*)&Pl[(k0+l15)*P18 + off];
        bf16x8 qh = *(const bf16x8*)&Qh[(l0+l15)*P18 + off];
        bf16x8 ql = *(const bf16x8*)&Ql[(l0+l15)*P18 + off];
        f32x4 a = (f32x4){0.f,0.f,0.f,0.f};
        a = __builtin_amdgcn_mfma_f32_16x16x32_bf16(ph, qh, a, 0,0,0);
        a = __builtin_amdgcn_mfma_f32_16x16x32_bf16(pl, qh, a, 0,0,0);
        a = __builtin_amdgcn_mfma_f32_16x16x32_bf16(ph, ql, a, 0,0,0);
        return a;
    };

    short *Xch = Xah, *Xcl = Xal, *Xnh = Xbh, *Xnl = Xbl;
    short *Xch8 = Xah8, *Xcl8 = Xal8, *Xnh8 = Xbh8, *Xnl8 = Xbl8;

    for (int it = 0; it < 10; ++it){
        f32x4 y0 = mmT(t0, Ah, Al, Xch, Xcl);
        f32x4 y1 = mmT(t1, Ah, Al, Xch, Xcl);
        f32x4 y2 = mmT(t2, Ah, Al, Xch, Xcl);
        f32x4 y8 = mm8(Bh8, Bl8, Xch8, Xcl8);
        auto wrZ = [&](int t, f32x4 a){
            if (t < 9){
                int k0 = (t/3)*16, l0 = (t%3)*16;
                #pragma unroll
                for (int r = 0; r < 4; ++r){
                    int k = k0 + lhi*4 + r, l = l0 + l15;
                    float z = ((k==l) ? 2.f : 0.f) - a[r];
                    short h = f2bf(z);
                    Zh[k*P47 + l] = h;
                    Zl[k*P47 + l] = f2bf(z - bf2f(h));
                }
            }
        };
        wrZ(t0,y0); wrZ(t1,y1); wrZ(t2,y2);
        {
            int k0 = (wv >> 1)*16, l0 = (wv & 1)*16;
            #pragma unroll
            for (int r = 0; r < 4; ++r){
                int k = k0 + lhi*4 + r, l = l0 + l15;
                float z = ((k==l) ? 2.f : 0.f) - y8[r];
                short h = f2bf(z);
                Zh8[k*P18 + l] = h;
                Zl8[k*P18 + l] = f2bf(z - bf2f(h));
            }
        }
        __syncthreads();
        f32x4 x0 = mmT(t0, Xch, Xcl, Zh, Zl);
        f32x4 x1 = mmT(t1, Xch, Xcl, Zh, Zl);
        f32x4 x2 = mmT(t2, Xch, Xcl, Zh, Zl);
        f32x4 x8 = mm8(Xch8, Xcl8, Zh8, Zl8);
        if (it < 9){
            auto wrX = [&](int t, f32x4 a){
                if (t < 9){
                    int k0 = (t/3)*16, l0 = (t%3)*16;
                    #pragma unroll
                    for (int r = 0; r < 4; ++r){
                        int k = k0 + lhi*4 + r, l = l0 + l15;
                        short h = f2bf(a[r]);
                        Xnh[k*P47 + l] = h;
                        Xnl[k*P47 + l] = f2bf(a[r] - bf2f(h));
                    }
                }
            };
            wrX(t0,x0); wrX(t1,x1); wrX(t2,x2);
            int k0 = (wv >> 1)*16, l0 = (wv & 1)*16;
            #pragma unroll
            for (int r = 0; r < 4; ++r){
                int k = k0 + lhi*4 + r, l = l0 + l15;
                short h = f2bf(x8[r]);
                Xnh8[k*P18 + l] = h;
                Xnl8[k*P18 + l] = f2bf(x8[r] - bf2f(h));
            }
        } else {
            auto wrF = [&](int t, f32x4 a){
                if (t < 9){
                    int k0 = (t/3)*16, l0 = (t%3)*16;
                    #pragma unroll
                    for (int r = 0; r < 4; ++r){
                        int k = k0 + lhi*4 + r, l = l0 + l15;
                        float v = (k < 47 && l < 47) ? a[r] : 0.f;
                        Ainvbf[k*64 + l] = f2bf(v);
                    }
                }
            };
            wrF(t0,x0); wrF(t1,x1); wrF(t2,x2);
            int k0 = (wv >> 1)*16, l0 = (wv & 1)*16;
            #pragma unroll
            for (int r = 0; r < 4; ++r){
                int k = k0 + lhi*4 + r, l = l0 + l15;
                if (k < 18 && l < 18) Ainv18[k*18 + l] = x8[r];
            }
        }
        __syncthreads();
        short* tp;
        tp = Xch; Xch = Xnh; Xnh = tp;
        tp = Xcl; Xcl = Xnl; Xnl = tp;
        tp = Xch8; Xch8 = Xnh8; Xnh8 = tp;
        tp = Xcl8; Xcl8 = Xnl8; Xnl8 = tp;
    }

    for (int e = tid; e < 48*16; e += 256){
        int k = e >> 4, j = e & 15;
        Ainvbf[k*64 + 48 + j] = 0;
    }
}

// ---------------------------------------------------------------------------
// Kernel 2: AQ_Tb = b @ AQ via split-bf16 MFMA; b staged through LDS with
// coalesced loads, double-buffered (rows padded to 36 floats).
// ---------------------------------------------------------------------------
__global__ __launch_bounds__(256) void aqtb_mfma(const float* __restrict__ b,
                                                 const short* __restrict__ Bseq,
                                                 float* __restrict__ AQ_Tb){
    __shared__ float blds[2][64][36];
    const int tid  = threadIdx.x;
    const int lane = tid & 63;
    const int wv   = tid >> 6;
    const int l15  = lane & 15;
    const int lhi  = lane >> 4;
    const int v0   = blockIdx.x*64;
    const int srow = tid >> 2;          // 0..63: staging row
    const int schk = (tid & 3)*8;       // 0,8,16,24: staging chunk
    const float* bsrc = b + (size_t)(v0 + srow)*NS;
    const short* bs = Bseq + lane*8;

    auto stage = [&](int s, int buf){
        int n0 = s*32 + schk;
        float* dst = &blds[buf][srow][schk];
        if (n0 + 8 <= NS){
            *(f32x4*)dst       = *(const f32x4*)(bsrc + n0);
            *(f32x4*)(dst + 4) = *(const f32x4*)(bsrc + n0 + 4);
        } else {
            #pragma unroll
            for (int j = 0; j < 8; ++j){
                int n = n0 + j;
                dst[j] = (n < NS) ? bsrc[n] : 0.f;
            }
        }
    };

    f32x4 acc[3];
    #pragma unroll
    for (int t = 0; t < 3; ++t) acc[t] = (f32x4){0.f,0.f,0.f,0.f};

    const int arow = wv*16 + l15;       // this thread's MFMA A row
    stage(0, 0);

    for (int step = 0; step < 10; ++step){
        __syncthreads();
        if (step + 1 < 10) stage(step + 1, (step + 1) & 1);
        const float* src = &blds[step & 1][arow][lhi*8];
        f32x4 q0 = *(const f32x4*)src;
        f32x4 q1 = *(const f32x4*)(src + 4);

        bf16x8 Ah, Al;
        #pragma unroll
        for (int j = 0; j < 4; ++j){
            short h0 = f2bf(q0[j]);
            Ah[j] = h0;
            Al[j] = f2bf(q0[j] - bf2f(h0));
            short h1 = f2bf(q1[j]);
            Ah[4 + j] = h1;
            Al[4 + j] = f2bf(q1[j] - bf2f(h1));
        }
        const short* bstep = bs + step*3072;
        #pragma unroll
        for (int t = 0; t < 3; ++t){
            bf16x8 Bh = *(const bf16x8*)(bstep + t*1024);
            bf16x8 Bl = *(const bf16x8*)(bstep + t*1024 + 512);
            acc[t] = __builtin_amdgcn_mfma_f32_16x16x32_bf16(Ah, Bh, acc[t], 0, 0, 0);
            acc[t] = __builtin_amdgcn_mfma_f32_16x16x32_bf16(Al, Bh, acc[t], 0, 0, 0);
            acc[t] = __builtin_amdgcn_mfma_f32_16x16x32_bf16(Ah, Bl, acc[t], 0, 0, 0);
        }
    }

    const int vbase = v0 + wv*16 + lhi*4;
    #pragma unroll
    for (int t = 0; t < 3; ++t){
        int k = t*16 + l15;
        if (k < NK){
            #pragma unroll
            for (int r = 0; r < 4; ++r)
                AQ_Tb[(size_t)(vbase + r)*48 + k] = acc[t][r];
        }
    }
}

// ---------------------------------------------------------------------------
// Kernel 4: c init — 18x18 solve per voxel; write x-interleaved c64.
// Writes all 8 groups (6,7 zeros) — R4 semantics.
// ---------------------------------------------------------------------------
__global__ void init_c(const float* __restrict__ AQ_Tb, const float* __restrict__ Ainv18,
                       short* __restrict__ c64, int nvox){
    int v = blockIdx.x*blockDim.x + threadIdx.x;
    if (v >= nvox) return;
    float rhs[18];
    {
        const float* row = AQ_Tb + (size_t)v*48;
        f32x4 r0 = *(const f32x4*)(row + 0);
        f32x4 r1 = *(const f32x4*)(row + 4);
        f32x4 r2 = *(const f32x4*)(row + 8);
        f32x4 r3 = *(const f32x4*)(row + 12);
        #pragma unroll
        for (int j = 0; j < 4; ++j){
            rhs[j] = r0[j]; rhs[4+j] = r1[j]; rhs[8+j] = r2[j]; rhs[12+j] = r3[j];
        }
        rhs[16] = row[45];
        rhs[17] = row[46];
    }
    short row[64];
    #pragma unroll
    for (int k = 0; k < 64; ++k) row[k] = 0;
    #pragma unroll
    for (int r = 0; r < 18; ++r){
        float acc = 0.f;
        #pragma unroll
        for (int j = 0; j < 18; ++j) acc += Ainv18[r*18 + j] * rhs[j];
        row[(r < 16) ? r : 29 + r] = f2bf(acc);
    }
    int x = v % 48; int t2 = v / 48; int y = t2 % 48; int z = t2 / 48;
    short* base = c64 + (size_t)(z*48 + y)*3072;   // 8 groups * 48 * 8
    #pragma unroll
    for (int g = 0; g < 8; ++g)
        *(bf16x8*)(base + (size_t)(g*48 + x)*8) = *(const bf16x8*)&row[g*8];
}

// ---------------------------------------------------------------------------
// Kernel 5: conv1 3x3x3 (47->96) + bias + ReLU via bf16 MFMA.
// 512 threads / 8 waves per block, tile 16x16x1 (grid.z = Mi): conv1 was
// GRID-STARVED at 1024-thr/16x16x2 (207 blocks < 256 CUs, 49 CUs idle,
// latency-bound at 4 waves/SIMD). Now 360-414 blocks, LDS 72KB -> 2
// blocks/CU co-residency. Wave map keeps R7's reuse-4: 4 y-quads (4 rows)
// x 2 och-halves, acc[4][3] — per-output math bit-identical.
// 9 phases (dz,dy): weight slice dbuf in LDS, XOR swizzle.
// ---------------------------------------------------------------------------
__device__ __forceinline__ void stage_w(const short* __restrict__ src, short* dst, int tid){
    #pragma unroll
    for (int it = 0; it < 5; ++it){
        int d = (it*512 + tid) * 16;
        if (d < 36864){
            bf16x8 v = *(const bf16x8*)((const char*)src + d);
            int ds = d ^ (((d >> 7) & 7) << 4);
            *(bf16x8*)((char*)dst + ds) = v;
        }
    }
}

__global__ __launch_bounds__(512, 2) void conv1_mfma(const short* __restrict__ c64,
                                                     const short* __restrict__ wbf,
                                                     const float* __restrict__ b1,
                                                     short* __restrict__ h,
                                                     int Ni, int Mi){
    __shared__ short wlds[2][18432];
    const int tid = threadIdx.x;
    const int lane = tid & 63;
    const int wid  = tid >> 6;        // 0..7
    const int w4   = wid >> 1;        // 0..3   y-quad (4 rows)
    const int th   = wid & 1;         // 0..1   och half
    const int l15 = lane & 15;
    const int lhi = lane >> 4;
    const int z0 = blockIdx.z;
    const int x0 = blockIdx.x * 16;
    const int yw = blockIdx.y * 16 + w4 * 4;

    f32x4 acc[4][3];
    #pragma unroll
    for (int yr = 0; yr < 4; ++yr)
        #pragma unroll
        for (int t = 0; t < 3; ++t) acc[yr][t] = (f32x4){0.f,0.f,0.f,0.f};

    stage_w(wbf, &wlds[0][0], tid);

    const int grpstride = Ni*8;             // shorts per g-plane within (z,y)
    for (int p = 0; p < 9; ++p){
        __syncthreads();
        if (p < 8) stage_w(wbf + (size_t)(p+1)*18432, &wlds[(p+1)&1][0], tid);
        const char* wb = (const char*)&wlds[p&1][0];
        const int dz = p / 3;
        const int dy = p - dz*3;
        const int gzN = (z0 + dz)*Ni;

        #pragma unroll
        for (int dx = 0; dx < 3; ++dx){
            int gx = min(x0 + l15 + dx, Ni-1);
            const short* arow[4];
            #pragma unroll
            for (int yr = 0; yr < 4; ++yr){
                int gy = min(yw + yr + dy, Ni-1);
                arow[yr] = c64 + (size_t)(gzN + gy)*Ni*64 + (size_t)lhi*grpstride + gx*8;
            }
            #pragma unroll
            for (int kk = 0; kk < 2; ++kk){
                bf16x8 a0 = *(const bf16x8*)(arow[0] + kk*4*grpstride);
                bf16x8 a1 = *(const bf16x8*)(arow[1] + kk*4*grpstride);
                bf16x8 a2 = *(const bf16x8*)(arow[2] + kk*4*grpstride);
                bf16x8 a3 = *(const bf16x8*)(arow[3] + kk*4*grpstride);
                #pragma unroll
                for (int t = 0; t < 3; ++t){
                    int tt = th*3 + t;
                    int d = ((dx*96 + tt*16 + l15)*64 + kk*32 + lhi*8) * 2;
                    d ^= ((d >> 7) & 7) << 4;
                    bf16x8 b = *(const bf16x8*)(wb + d);
                    acc[0][t] = __builtin_amdgcn_mfma_f32_16x16x32_bf16(a0, b, acc[0][t], 0, 0, 0);
                    acc[1][t] = __builtin_amdgcn_mfma_f32_16x16x32_bf16(a1, b, acc[1][t], 0, 0, 0);
                    acc[2][t] = __builtin_amdgcn_mfma_f32_16x16x32_bf16(a2, b, acc[2][t], 0, 0, 0);
                    acc[3][t] = __builtin_amdgcn_mfma_f32_16x16x32_bf16(a3, b, acc[3][t], 0, 0, 0);
                }
            }
        }
    }

    #pragma unroll
    for (int yr = 0; yr < 4; ++yr){
        int yy = yw + yr;
        if (yy >= Mi) continue;
        #pragma unroll
        for (int t = 0; t < 3; ++t){
            int och = th*48 + t*16 + l15;
            float bias = b1[och];
            #pragma unroll
            for (int r = 0; r < 4; ++r){
                int xx = x0 + lhi*4 + r;
                if (xx < Mi){
                    size_t vo = ((size_t)(z0*Mi + yy)*Mi + xx)*NHID + och;
                    h[vo] = f2bf(fmaxf(acc[yr][t][r] + bias, 0.f));
                }
            }
        }
    }
}

// ---------------------------------------------------------------------------
// Kernel 6: fused MFMA conv2+ReLU -> conv3 -> gate -> rhs -> 47x47 solve.
// c64out / cin64 in x-interleaved layout; pad groups 6,7 written as zeros.
// bufA/bufB rows padded to 112 shorts (224B, 16B-aligned). conv3 output is
// written position-shifted (o>=47 -> o+1) so gate partner of k sits at 48+k:
// both gate operands become aligned bf16x8 LDS reads; cin64/AQ_Tb gathers
// become 16B/32B vector loads. rhsL at stride 64 (pad 48..63 zeroed).
// ---------------------------------------------------------------------------
__global__ __launch_bounds__(256) void cascade_mfma(const short* __restrict__ h,
                                                    const short* __restrict__ cin64,
                                                    const float* __restrict__ AQ_Tb,
                                                    const short* __restrict__ w2bf,
                                                    const float* __restrict__ b2,
                                                    const short* __restrict__ w3bf,
                                                    const float* __restrict__ b3,
                                                    const short* __restrict__ Ainvbf,
                                                    const float* __restrict__ dreg_p,
                                                    short* __restrict__ c64out,
                                                    float* __restrict__ fout,
                                                    int Mi, int off, int iter, int final_i){
    __shared__ short bufA[64][112];
    __shared__ short bufB[64][112];
    const int tid = threadIdx.x;
    const int lane = tid & 63;
    const int wv  = tid >> 6;
    const int l15 = lane & 15;
    const int lhi = lane >> 4;
    const int nvox = Mi*Mi*Mi;
    const int v0 = blockIdx.x * 64;
    const float dreg = dreg_p[0];

    for (int f = tid; f < 64*12; f += 256){
        int v = f / 12, c = f % 12;
        int gv = v0 + v;
        bf16x8 val = (bf16x8){0,0,0,0,0,0,0,0};
        if (gv < nvox) val = *(const bf16x8*)(h + (size_t)gv*NHID + c*8);
        *(bf16x8*)&bufA[v][c*8] = val;
    }
    __syncthreads();

    const int vox = wv*16 + l15;

    {   // conv2 + bias + ReLU -> bufB
        f32x4 acc2[6];
        #pragma unroll
        for (int m = 0; m < 6; ++m) acc2[m] = (f32x4){0.f,0.f,0.f,0.f};
        #pragma unroll
        for (int ks = 0; ks < 3; ++ks){
            bf16x8 bfr = *(const bf16x8*)&bufA[vox][lhi*8 + ks*32];
            #pragma unroll
            for (int m = 0; m < 6; ++m){
                bf16x8 a = *(const bf16x8*)(w2bf + (size_t)(m*16 + l15)*96 + lhi*8 + ks*32);
                acc2[m] = __builtin_amdgcn_mfma_f32_16x16x32_bf16(a, bfr, acc2[m], 0, 0, 0);
            }
        }
        #pragma unroll
        for (int m = 0; m < 6; ++m){
            int o0 = m*16 + lhi*4;
            float x0 = fmaxf(acc2[m][0] + b2[o0+0], 0.f);
            float x1 = fmaxf(acc2[m][1] + b2[o0+1], 0.f);
            float x2 = fmaxf(acc2[m][2] + b2[o0+2], 0.f);
            float x3 = fmaxf(acc2[m][3] + b2[o0+3], 0.f);
            *(unsigned*)&bufB[vox][o0]     = pk(f2bf(x0), f2bf(x1));
            *(unsigned*)&bufB[vox][o0 + 2] = pk(f2bf(x2), f2bf(x3));
        }
    }

    {   // conv3 + bias -> bufA (cc); wave-private rows, no barrier needed
        // positions shifted: och o stored at o + (o>=47)
        f32x4 acc3[6];
        #pragma unroll
        for (int m = 0; m < 6; ++m) acc3[m] = (f32x4){0.f,0.f,0.f,0.f};
        #pragma unroll
        for (int ks = 0; ks < 3; ++ks){
            bf16x8 bfr = *(const bf16x8*)&bufB[vox][lhi*8 + ks*32];
            #pragma unroll
            for (int m = 0; m < 6; ++m){
                bf16x8 a = *(const bf16x8*)(w3bf + (size_t)(m*16 + l15)*96 + lhi*8 + ks*32);
                acc3[m] = __builtin_amdgcn_mfma_f32_16x16x32_bf16(a, bfr, acc3[m], 0, 0, 0);
            }
        }
        #pragma unroll
        for (int m = 0; m < 6; ++m){
            int o0 = m*16 + lhi*4;
            float xv[4];
            #pragma unroll
            for (int e = 0; e < 4; ++e){
                int o = o0 + e;
                xv[e] = (o < 94) ? acc3[m][e] + b3[o] : 0.f;
            }
            if (o0 + 3 < 47){
                *(unsigned*)&bufA[vox][o0]     = pk(f2bf(xv[0]), f2bf(xv[1]));
                *(unsigned*)&bufA[vox][o0 + 2] = pk(f2bf(xv[2]), f2bf(xv[3]));
            } else {
                #pragma unroll
                for (int e = 0; e < 4; ++e){
                    int o = o0 + e;
                    bufA[vox][o + (o >= 47)] = f2bf(xv[e]);
                }
            }
        }
    }
    __syncthreads();

    short (*rhsL)[64] = (short(*)[64])&bufB[0][0];
    {   // gate + rhs (vectorized: bf16x8 cin/LDS reads, f32x4 AQ_Tb reads)
        int v = tid >> 2, q = tid & 3;
        int gv = v0 + v;
        int z = 0, y = 0, x = 0;
        bool live = (gv < nvox);
        if (live){
            z = gv / (Mi*Mi);
            int r = gv % (Mi*Mi);
            y = r / Mi; x = r % Mi;
        }
        const int Nin = Mi + 2;
        const size_t rbase = (size_t)((z+1)*Nin + (y+1))*Nin*64;
        const float* aqr = AQ_Tb + ((size_t)((z+off)*NFULL + (y+off))*NFULL + (x+off))*48;

        auto do_group = [&](int g){
            const int k0 = g*8;
            bf16x8 cc1 = *(const bf16x8*)&bufA[v][k0];
            bf16x8 cc2 = *(const bf16x8*)&bufA[v][48 + k0];
            bf16x8 cv = (bf16x8){0,0,0,0,0,0,0,0};
            if (iter > 0)
                cv = *(const bf16x8*)&cin64[rbase + (size_t)(g*Nin + (x+1))*8];
            f32x4 aq0 = *(const f32x4*)(aqr + k0);
            f32x4 aq1 = *(const f32x4*)(aqr + k0 + 4);
            short outs[8];
            #pragma unroll
            for (int j = 0; j < 8; ++j){
                int k = k0 + j;
                if (live && k < 47){
                    float gt = bf2f(cc1[j]) * sigmoidf(bf2f(cc2[j]));
                    if (iter > 0) gt += bf2f(cv[j]);
                    float aq = (j < 4) ? aq0[j] : aq1[j-4];
                    outs[j] = f2bf(aq + dreg * gt);
                } else outs[j] = 0;
            }
            *(bf16x8*)&rhsL[v][k0] = *(const bf16x8*)outs;
        };
        do_group(q);
        if (q < 2){
            do_group(q + 4);
        } else {
            // zero pad groups 6,7 (k 48..63) of the solve input
            *(bf16x8*)&rhsL[v][48 + (q - 2)*8] = (bf16x8){0,0,0,0,0,0,0,0};
        }
    }
    __syncthreads();

    {   // 47x47 solve
        f32x4 accS[3];
        #pragma unroll
        for (int m = 0; m < 3; ++m) accS[m] = (f32x4){0.f,0.f,0.f,0.f};
        #pragma unroll
        for (int ks = 0; ks < 2; ++ks){
            bf16x8 bfr = *(const bf16x8*)&rhsL[vox][lhi*8 + ks*32];
            #pragma unroll
            for (int m = 0; m < 3; ++m){
                bf16x8 a = *(const bf16x8*)(Ainvbf + (size_t)(m*16 + l15)*64 + lhi*8 + ks*32);
                accS[m] = __builtin_amdgcn_mfma_f32_16x16x32_bf16(a, bfr, accS[m], 0, 0, 0);
            }
        }
        int gv = v0 + vox;
        if (gv < nvox){
            if (final_i){
                #pragma unroll
                for (int m = 0; m < 3; ++m){
                    int k0 = m*16 + lhi*4;
                    #pragma unroll
                    for (int r = 0; r < 4; ++r){
                        int k = k0 + r;
                        if (k < 47) fout[(size_t)gv*NK + k] = accS[m][r];
                    }
                }
            } else {
                int z = gv / (Mi*Mi);
                int rr = gv % (Mi*Mi);
                int y = rr / Mi, x = rr % Mi;
                short* base = c64out + (size_t)(z*Mi + y)*Mi*64;
                #pragma unroll
                for (int m = 0; m < 3; ++m){
                    int k0 = m*16 + lhi*4;
                    int g = k0 >> 3, j = k0 & 7;
                    short s0 = f2bf(accS[m][0]);
                    short s1 = f2bf(accS[m][1]);
                    short s2 = f2bf(accS[m][2]);
                    short s3 = (k0 + 3 < 47) ? f2bf(accS[m][3]) : (short)0;
                    short* ad = base + (size_t)(g*Mi + x)*8 + j;
                    *(unsigned*)(ad)     = pk(s0, s1);
                    *(unsigned*)(ad + 2) = pk(s2, s3);
                }
            }
        }
    }

    if (!final_i){   // zero pad channels 48..63 (g-planes 6,7)
        for (int f = tid; f < 64*8; f += 256){
            int v = f >> 3, gv = v0 + v;
            if (gv < nvox){
                int u = f & 7;
                int c = 48 + u*2;
                int g = c >> 3, j = c & 7;
                int z = gv / (Mi*Mi);
                int rr = gv % (Mi*Mi);
                int y = rr / Mi, x = rr % Mi;
                *(unsigned*)&c64out[(size_t)(z*Mi + y)*Mi*64 + (size_t)(g*Mi + x)*8 + j] = 0;
            }
        }
    }
}

// ---------------------------------------------------------------------------
extern "C" void kernel_launch(void* const* d_in, const int* in_sizes, int n_in,
                              void* d_out, int out_size, void* d_ws, size_t ws_size,
                              hipStream_t stream){
    const float* b    = (const float*)d_in[0];
    const float* AQ   = (const float*)d_in[1];
    const float* w1   = (const float*)d_in[2];
    const float* b1   = (const float*)d_in[3];
    const float* w2   = (const float*)d_in[4];
    const float* b2   = (const float*)d_in[5];
    const float* w3   = (const float*)d_in[6];
    const float* b3   = (const float*)d_in[7];
    const float* dreg = (const float*)d_in[8];
    float* out = (float*)d_out;
    float* ws  = (float*)d_ws;

    const size_t NV48 = (size_t)48*48*48;                 // 110592
    float* Ainv18 = ws;                                    // 336
    float* AQ_Tb  = ws + 336;                              // NV48*48 (rows padded)
    short* hbuf   = (short*)(AQ_Tb + NV48*48);             // 46^3*96
    short* w1bf   = hbuf + (size_t)46*46*46*NHID;          // 4*27*96*64
    short* w2bf   = w1bf + (size_t)4*27*96*64;             // 4*96*96
    short* w3bf   = w2bf + (size_t)4*96*96;                // 4*96*96
    short* Ainvbf = w3bf + (size_t)4*96*96;                // 48*64
    short* Bseq   = Ainvbf + 48*64;                        // 30720
    short* c64A   = Bseq + 30720;                          // NV48*64 + slack
    short* c64B   = c64A + NV48*64 + 32768;

    prep_small<<<45, 256, 0, stream>>>(AQ, dreg, Ainv18, Ainvbf, Bseq,
                                       w1, w1bf, w2, w3, w2bf, w3bf);
    aqtb_mfma<<<(int)(NV48/64), 256, 0, stream>>>(b, Bseq, AQ_Tb);
    init_c<<<(int)((NV48 + 255)/256), 256, 0, stream>>>(AQ_Tb, Ainv18, c64A, (int)NV48);

    short* ccur = c64A;
    short* cnext = c64B;
    for (int i = 0; i < 4; ++i){
        int Ni = 48 - 2*i;
        int Mi = Ni - 2;
        dim3 g1((Mi + 15)/16, (Mi + 15)/16, Mi);
        conv1_mfma<<<g1, 512, 0, stream>>>(ccur, w1bf + (size_t)i*27*96*64, b1 + i*96,
                                           hbuf, Ni, Mi);
        int nv = Mi*Mi*Mi;
        int fin = (i == 3) ? 1 : 0;
        cascade_mfma<<<(nv + 63)/64, 256, 0, stream>>>(
            hbuf, ccur, AQ_Tb, w2bf + (size_t)i*9216, b2 + i*96,
            w3bf + (size_t)i*9216, b3 + i*94, Ainvbf, dreg, cnext, out, Mi, i+1, i, fin);
        short* t = ccur; ccur = cnext; cnext = t;
    }
}

// Round 11
// 384.460 us; speedup vs baseline: 1.2097x; 1.2097x over previous
//
#include <hip/hip_runtime.h>
#include <math.h>

#define NS 300
#define NK 47
#define NHID 96
#define NFULL 48

typedef __attribute__((ext_vector_type(8))) short bf16x8;
typedef __attribute__((ext_vector_type(4))) float f32x4;
typedef __attribute__((ext_vector_type(4))) short s16x4;

__device__ __forceinline__ float sigmoidf(float x){ return 1.0f/(1.0f+expf(-x)); }
__device__ __forceinline__ short f2bf(float f){
    union { float f; unsigned u; } v; v.f = f;
    unsigned r = v.u + 0x7fffu + ((v.u >> 16) & 1u);
    return (short)(r >> 16);
}
__device__ __forceinline__ float bf2f(short s){
    union { unsigned u; float f; } v; v.u = ((unsigned)(unsigned short)s) << 16;
    return v.f;
}
__device__ __forceinline__ unsigned pk(short lo, short hi){
    return (unsigned)(unsigned short)lo | ((unsigned)(unsigned short)hi << 16);
}

// c-tensor layout (all c64 buffers): addr(z,y,g,x,j) = ((z*N+y)*8+g)*N*8 + x*8 + j
//   g = ci>>3 (0..7), j = ci&7.  A 16-lane x-slice at fixed g is 256B contiguous.
// Groups 6,7 hold zeros — R4 semantics.
// AQ_Tb rows padded to 48 floats (192B, 16B-aligned) for vector loads.

// ---------------------------------------------------------------------------
// Kernel 1 (merged prologue): block 0 = AQT split-bf16 Gram47 + Newton-Schulz
// inverses (A47+dreg pad48, A18+0.01 pad32) + Bseq; blocks 1..41 = w1->bf16
// conversion; blocks 42..44 = w2/w3->bf16.
// ---------------------------------------------------------------------------
#define AQP 328
#define P47 72
#define P18 40
__global__ __launch_bounds__(256) void prep_small(const float* __restrict__ AQ,
                           const float* __restrict__ dreg_p,
                           float* __restrict__ Ainv18, short* __restrict__ Ainvbf,
                           short* __restrict__ Bseq,
                           const float* __restrict__ w1, short* __restrict__ w1bf,
                           const float* __restrict__ w2, const float* __restrict__ w3,
                           short* __restrict__ w2bf, short* __restrict__ w3bf){
    __shared__ __align__(16) char smem[93824];

    const int tid = threadIdx.x;
    const int blk = blockIdx.x;

    if (blk >= 1){
        if (blk <= 41){
            int idx = (blk - 1)*256 + tid;
            if (idx < 4*27*96){
                int o = idx % 96; int rest = idx / 96; int s = rest % 27; int i = rest / 27;
                const float* src = w1 + ((size_t)i*96 + o)*1269 + s;
                short* dst = w1bf + (size_t)idx*64;
                #pragma unroll
                for (int ci = 0; ci < 47; ++ci) dst[ci] = f2bf(src[ci*27]);
                #pragma unroll
                for (int ci = 47; ci < 64; ++ci) dst[ci] = 0;
            }
        } else {
            int idx = (blk - 42)*256 + tid;
            if (idx < 768){
                if (idx < 384){
                    const float* src = w2 + (size_t)idx*96;
                    short* dst = w2bf + (size_t)idx*96;
                    for (int k = 0; k < 96; ++k) dst[k] = f2bf(src[k]);
                } else {
                    int j = idx - 384;
                    int i = j / 96, o = j % 96;
                    short* dst = w3bf + (size_t)j*96;
                    if (o < 94){
                        const float* src = w3 + ((size_t)i*94 + o)*96;
                        for (int k = 0; k < 96; ++k) dst[k] = f2bf(src[k]);
                    } else {
                        for (int k = 0; k < 96; ++k) dst[k] = 0;
                    }
                }
            }
        }
        return;
    }

    short* AQh = (short*)smem;
    short* AQl = AQh + 48*AQP;
    float* Gf  = (float*)(smem + 62976);
    short* M47 = (short*)smem;
    short* M18 = (short*)(smem + 72960);
    float* rs47 = (float*)(smem + 93440);
    float* rs18 = rs47 + 48;
    float* shc  = rs18 + 32;

    const int lane = tid & 63;
    const int wv  = tid >> 6;
    const int l15 = lane & 15;
    const int lhi = lane >> 4;
    const float dreg = dreg_p[0];

    #pragma unroll 4
    for (int idx = tid; idx < 48*AQP; idx += 256){
        int k = idx / AQP, n = idx - k*AQP;
        float a = (k < 47 && n < 300) ? AQ[n*NK + k] : 0.f;
        short h = f2bf(a);
        short l = f2bf(a - bf2f(h));
        AQh[idx] = h; AQl[idx] = l;
        if (n < 320){
            int step = n >> 5, lh = (n >> 3) & 3, j = n & 7;
            int t = k >> 4, kl = k & 15;
            int base = ((step*3 + t)*2)*512 + (lh*16 + kl)*8 + j;
            Bseq[base]       = h;
            Bseq[base + 512] = l;
        }
    }
    __syncthreads();

    const int t0 = wv, t1 = wv + 4, t2 = wv + 8;
    f32x4 g0, g1, g2;
    {
        auto gram = [&](int t) -> f32x4 {
            int tt = (t < 9) ? t : t - 9;
            int k0 = (tt/3)*16, l0 = (tt%3)*16;
            f32x4 a = (f32x4){0.f,0.f,0.f,0.f};
            for (int ks = 0; ks < 10; ++ks){
                int off = ks*32 + lhi*8;
                bf16x8 ph = *(const bf16x8*)&AQh[(k0+l15)*AQP + off];
                bf16x8 pl = *(const bf16x8*)&AQl[(k0+l15)*AQP + off];
                bf16x8 qh = *(const bf16x8*)&AQh[(l0+l15)*AQP + off];
                bf16x8 ql = *(const bf16x8*)&AQl[(l0+l15)*AQP + off];
                a = __builtin_amdgcn_mfma_f32_16x16x32_bf16(ph, qh, a, 0,0,0);
                a = __builtin_amdgcn_mfma_f32_16x16x32_bf16(pl, qh, a, 0,0,0);
                a = __builtin_amdgcn_mfma_f32_16x16x32_bf16(ph, ql, a, 0,0,0);
            }
            return a;
        };
        g0 = gram(t0); g1 = gram(t1); g2 = gram(t2);
    }
    __syncthreads();

    for (int i = tid; i < 8*48*P47; i += 256) M47[i] = 0;
    for (int i = tid; i < 8*32*P18; i += 256) M18[i] = 0;
    {
        auto wrG = [&](int t, f32x4 a){
            if (t < 9){
                int k0 = (t/3)*16, l0 = (t%3)*16;
                #pragma unroll
                for (int r = 0; r < 4; ++r)
                    Gf[(k0 + lhi*4 + r)*52 + (l0 + l15)] = a[r];
            }
        };
        wrG(t0,g0); wrG(t1,g1); wrG(t2,g2);
    }
    __syncthreads();

    short* Ah  = M47;            short* Al  = M47 + 3456;
    short* Xah = M47 + 2*3456;   short* Xal = M47 + 3*3456;
    short* Xbh = M47 + 4*3456;   short* Xbl = M47 + 5*3456;
    short* Zh  = M47 + 6*3456;   short* Zl  = M47 + 7*3456;
    short* Bh8 = M18;            short* Bl8 = M18 + 1280;
    short* Xah8= M18 + 2*1280;   short* Xal8= M18 + 3*1280;
    short* Xbh8= M18 + 4*1280;   short* Xbl8= M18 + 5*1280;
    short* Zh8 = M18 + 6*1280;   short* Zl8 = M18 + 7*1280;

    {
        auto wrA = [&](int t, f32x4 a){
            if (t < 9){
                int k0 = (t/3)*16, l0 = (t%3)*16;
                #pragma unroll
                for (int r = 0; r < 4; ++r){
                    int k = k0 + lhi*4 + r, l = l0 + l15;
                    float v = (k < 47 && l < 47) ? a[r] + (k==l ? dreg : 0.f)
                                                 : ((k==l) ? 1.f : 0.f);
                    short h = f2bf(v);
                    Ah[k*P47 + l] = h;
                    Al[k*P47 + l] = f2bf(v - bf2f(h));
                }
            }
        };
        wrA(t0,g0); wrA(t1,g1); wrA(t2,g2);
    }
    if (tid < 48){
        float s = 1.f;
        if (tid < 47){
            s = dreg;
            for (int l = 0; l < 47; ++l) s += fabsf(Gf[tid*52 + l]);
        }
        rs47[tid] = s;
    }
    if (tid >= 64 && tid < 96){
        int r = tid - 64;
        float s = 1.f;
        if (r < 18){
            int gk = (r < 16) ? r : r + 29;
            s = 0.f;
            for (int l = 0; l < 18; ++l){
                int gl = (l < 16) ? l : l + 29;
                s += fabsf(Gf[gk*52 + gl] + ((l==r) ? 0.01f : 0.f));
            }
        }
        rs18[r] = s;
    }
    for (int e = tid; e < 32*32; e += 256){
        int k = e >> 5, l = e & 31;
        float v;
        if (k < 18 && l < 18){
            int gk = (k < 16) ? k : k + 29;
            int gl = (l < 16) ? l : l + 29;
            v = Gf[gk*52 + gl] + ((k==l) ? 0.01f : 0.f);
        } else v = (k==l) ? 1.f : 0.f;
        short h = f2bf(v);
        Bh8[k*P18 + l] = h;
        Bl8[k*P18 + l] = f2bf(v - bf2f(h));
    }
    __syncthreads();

    if (tid == 0){
        float m = 0.f;
        for (int i = 0; i < 48; ++i) m = fmaxf(m, rs47[i]);
        shc[0] = 1.f / m;
    }
    if (tid == 1){
        float m = 0.f;
        for (int i = 0; i < 32; ++i) m = fmaxf(m, rs18[i]);
        shc[1] = 1.f / m;
    }
    __syncthreads();

    if (tid < 48){
        float c = shc[0];
        short h = f2bf(c);
        Xah[tid*P47 + tid] = h;
        Xal[tid*P47 + tid] = f2bf(c - bf2f(h));
    } else if (tid >= 64 && tid < 96){
        int r = tid - 64;
        float c = shc[1];
        short h = f2bf(c);
        Xah8[r*P18 + r] = h;
        Xal8[r*P18 + r] = f2bf(c - bf2f(h));
    }
    __syncthreads();

    auto mmT = [&](int t, const short* Ph, const short* Pl,
                   const short* Qh, const short* Ql) -> f32x4 {
        int tt = (t < 9) ? t : t - 9;
        int k0 = (tt/3)*16, l0 = (tt%3)*16;
        f32x4 a = (f32x4){0.f,0.f,0.f,0.f};
        #pragma unroll
        for (int kk = 0; kk < 2; ++kk){
            int off = kk*32 + lhi*8;
            bf16x8 ph = *(const bf16x8*)&Ph[(k0+l15)*P47 + off];
            bf16x8 pl = *(const bf16x8*)&Pl[(k0+l15)*P47 + off];
            bf16x8 qh = *(const bf16x8*)&Qh[(l0+l15)*P47 + off];
            bf16x8 ql = *(const bf16x8*)&Ql[(l0+l15)*P47 + off];
            a = __builtin_amdgcn_mfma_f32_16x16x32_bf16(ph, qh, a, 0,0,0);
            a = __builtin_amdgcn_mfma_f32_16x16x32_bf16(pl, qh, a, 0,0,0);
            a = __builtin_amdgcn_mfma_f32_16x16x32_bf16(ph, ql, a, 0,0,0);
        }
        return a;
    };
    auto mm8 = [&](const short* Ph, const short* Pl,
                   const short* Qh, const short* Ql) -> f32x4 {
        int k0 = (wv >> 1)*16, l0 = (wv & 1)*16;
        int off = lhi*8;
        bf16x8 ph = *(const bf16x8*)&Ph[(k0+l15)*P18 + off];
        bf16x8 pl = *(const bf16x8*)&Pl[(k0+l15)*P18 + off];
        bf16x8 qh = *(const bf16x8*)&Qh[(l0+l15)*P18 + off];
        bf16x8 ql = *(const bf16x8*)&Ql[(l0+l15)*P18 + off];
        f32x4 a = (f32x4){0.f,0.f,0.f,0.f};
        a = __builtin_amdgcn_mfma_f32_16x16x32_bf16(ph, qh, a, 0,0,0);
        a = __builtin_amdgcn_mfma_f32_16x16x32_bf16(pl, qh, a, 0,0,0);
        a = __builtin_amdgcn_mfma_f32_16x16x32_bf16(ph, ql, a, 0,0,0);
        return a;
    };

    short *Xch = Xah, *Xcl = Xal, *Xnh = Xbh, *Xnl = Xbl;
    short *Xch8 = Xah8, *Xcl8 = Xal8, *Xnh8 = Xbh8, *Xnl8 = Xbl8;

    for (int it = 0; it < 10; ++it){
        f32x4 y0 = mmT(t0, Ah, Al, Xch, Xcl);
        f32x4 y1 = mmT(t1, Ah, Al, Xch, Xcl);
        f32x4 y2 = mmT(t2, Ah, Al, Xch, Xcl);
        f32x4 y8 = mm8(Bh8, Bl8, Xch8, Xcl8);
        auto wrZ = [&](int t, f32x4 a){
            if (t < 9){
                int k0 = (t/3)*16, l0 = (t%3)*16;
                #pragma unroll
                for (int r = 0; r < 4; ++r){
                    int k = k0 + lhi*4 + r, l = l0 + l15;
                    float z = ((k==l) ? 2.f : 0.f) - a[r];
                    short h = f2bf(z);
                    Zh[k*P47 + l] = h;
                    Zl[k*P47 + l] = f2bf(z - bf2f(h));
                }
            }
        };
        wrZ(t0,y0); wrZ(t1,y1); wrZ(t2,y2);
        {
            int k0 = (wv >> 1)*16, l0 = (wv & 1)*16;
            #pragma unroll
            for (int r = 0; r < 4; ++r){
                int k = k0 + lhi*4 + r, l = l0 + l15;
                float z = ((k==l) ? 2.f : 0.f) - y8[r];
                short h = f2bf(z);
                Zh8[k*P18 + l] = h;
                Zl8[k*P18 + l] = f2bf(z - bf2f(h));
            }
        }
        __syncthreads();
        f32x4 x0 = mmT(t0, Xch, Xcl, Zh, Zl);
        f32x4 x1 = mmT(t1, Xch, Xcl, Zh, Zl);
        f32x4 x2 = mmT(t2, Xch, Xcl, Zh, Zl);
        f32x4 x8 = mm8(Xch8, Xcl8, Zh8, Zl8);
        if (it < 9){
            auto wrX = [&](int t, f32x4 a){
                if (t < 9){
                    int k0 = (t/3)*16, l0 = (t%3)*16;
                    #pragma unroll
                    for (int r = 0; r < 4; ++r){
                        int k = k0 + lhi*4 + r, l = l0 + l15;
                        short h = f2bf(a[r]);
                        Xnh[k*P47 + l] = h;
                        Xnl[k*P47 + l] = f2bf(a[r] - bf2f(h));
                    }
                }
            };
            wrX(t0,x0); wrX(t1,x1); wrX(t2,x2);
            int k0 = (wv >> 1)*16, l0 = (wv & 1)*16;
            #pragma unroll
            for (int r = 0; r < 4; ++r){
                int k = k0 + lhi*4 + r, l = l0 + l15;
                short h = f2bf(x8[r]);
                Xnh8[k*P18 + l] = h;
                Xnl8[k*P18 + l] = f2bf(x8[r] - bf2f(h));
            }
        } else {
            auto wrF = [&](int t, f32x4 a){
                if (t < 9){
                    int k0 = (t/3)*16, l0 = (t%3)*16;
                    #pragma unroll
                    for (int r = 0; r < 4; ++r){
                        int k = k0 + lhi*4 + r, l = l0 + l15;
                        float v = (k < 47 && l < 47) ? a[r] : 0.f;
                        Ainvbf[k*64 + l] = f2bf(v);
                    }
                }
            };
            wrF(t0,x0); wrF(t1,x1); wrF(t2,x2);
            int k0 = (wv >> 1)*16, l0 = (wv & 1)*16;
            #pragma unroll
            for (int r = 0; r < 4; ++r){
                int k = k0 + lhi*4 + r, l = l0 + l15;
                if (k < 18 && l < 18) Ainv18[k*18 + l] = x8[r];
            }
        }
        __syncthreads();
        short* tp;
        tp = Xch; Xch = Xnh; Xnh = tp;
        tp = Xcl; Xcl = Xnl; Xnl = tp;
        tp = Xch8; Xch8 = Xnh8; Xnh8 = tp;
        tp = Xcl8; Xcl8 = Xnl8; Xnl8 = tp;
    }

    for (int e = tid; e < 48*16; e += 256){
        int k = e >> 4, j = e & 15;
        Ainvbf[k*64 + 48 + j] = 0;
    }
}

// ---------------------------------------------------------------------------
// Kernel 2 (FUSED aqtb + init_c): AQ_Tb = b @ AQ via split-bf16 MFMA with
// LDS-staged coalesced b loads (double-buffered, rows padded to 36 floats),
// then the 18x18 init solve runs in-block on the fresh accumulators (dumped
// to LDS overlaying the dead b-staging buffer) — identical fp32 bits to the
// old init_c's AQ_Tb read-back, so bit-exact. Saves a launch + 21MB re-read.
// ---------------------------------------------------------------------------
__global__ __launch_bounds__(256) void aqtb_mfma(const float* __restrict__ b,
                                                 const short* __restrict__ Bseq,
                                                 const float* __restrict__ Ainv18,
                                                 float* __restrict__ AQ_Tb,
                                                 short* __restrict__ c64){
    __shared__ float blds[2][64][36];
    const int tid  = threadIdx.x;
    const int lane = tid & 63;
    const int wv   = tid >> 6;
    const int l15  = lane & 15;
    const int lhi  = lane >> 4;
    const int v0   = blockIdx.x*64;
    const int srow = tid >> 2;          // 0..63: staging row
    const int schk = (tid & 3)*8;       // 0,8,16,24: staging chunk
    const float* bsrc = b + (size_t)(v0 + srow)*NS;
    const short* bs = Bseq + lane*8;

    auto stage = [&](int s, int buf){
        int n0 = s*32 + schk;
        float* dst = &blds[buf][srow][schk];
        if (n0 + 8 <= NS){
            *(f32x4*)dst       = *(const f32x4*)(bsrc + n0);
            *(f32x4*)(dst + 4) = *(const f32x4*)(bsrc + n0 + 4);
        } else {
            #pragma unroll
            for (int j = 0; j < 8; ++j){
                int n = n0 + j;
                dst[j] = (n < NS) ? bsrc[n] : 0.f;
            }
        }
    };

    f32x4 acc[3];
    #pragma unroll
    for (int t = 0; t < 3; ++t) acc[t] = (f32x4){0.f,0.f,0.f,0.f};

    const int arow = wv*16 + l15;       // this thread's MFMA A row
    stage(0, 0);

    for (int step = 0; step < 10; ++step){
        __syncthreads();
        if (step + 1 < 10) stage(step + 1, (step + 1) & 1);
        const float* src = &blds[step & 1][arow][lhi*8];
        f32x4 q0 = *(const f32x4*)src;
        f32x4 q1 = *(const f32x4*)(src + 4);

        bf16x8 Ah, Al;
        #pragma unroll
        for (int j = 0; j < 4; ++j){
            short h0 = f2bf(q0[j]);
            Ah[j] = h0;
            Al[j] = f2bf(q0[j] - bf2f(h0));
            short h1 = f2bf(q1[j]);
            Ah[4 + j] = h1;
            Al[4 + j] = f2bf(q1[j] - bf2f(h1));
        }
        const short* bstep = bs + step*3072;
        #pragma unroll
        for (int t = 0; t < 3; ++t){
            bf16x8 Bh = *(const bf16x8*)(bstep + t*1024);
            bf16x8 Bl = *(const bf16x8*)(bstep + t*1024 + 512);
            acc[t] = __builtin_amdgcn_mfma_f32_16x16x32_bf16(Ah, Bh, acc[t], 0, 0, 0);
            acc[t] = __builtin_amdgcn_mfma_f32_16x16x32_bf16(Al, Bh, acc[t], 0, 0, 0);
            acc[t] = __builtin_amdgcn_mfma_f32_16x16x32_bf16(Ah, Bl, acc[t], 0, 0, 0);
        }
    }

    // ---- global AQ_Tb store (unchanged layout) ----
    const int vbase = v0 + wv*16 + lhi*4;
    #pragma unroll
    for (int t = 0; t < 3; ++t){
        int k = t*16 + l15;
        if (k < NK){
            #pragma unroll
            for (int r = 0; r < 4; ++r)
                AQ_Tb[(size_t)(vbase + r)*48 + k] = acc[t][r];
        }
    }

    // ---- fused init_c: dump acc -> LDS (overlay b-staging), solve 18x18 ----
    __syncthreads();                       // blds dead after step 9
    float* sol = &blds[0][0][0];           // 64 rows x 48 floats = 12288B
    #pragma unroll
    for (int t = 0; t < 3; ++t){
        int k = t*16 + l15;
        if (k < NK){
            #pragma unroll
            for (int r = 0; r < 4; ++r)
                sol[(wv*16 + lhi*4 + r)*48 + k] = acc[t][r];
        }
    }
    __syncthreads();

    if (tid < 64){
        int v = v0 + tid;
        const float* row = sol + tid*48;
        float rhs[18];
        #pragma unroll
        for (int j = 0; j < 16; ++j) rhs[j] = row[j];
        rhs[16] = row[45];
        rhs[17] = row[46];
        short orow[64];
        #pragma unroll
        for (int k = 0; k < 64; ++k) orow[k] = 0;
        #pragma unroll
        for (int r = 0; r < 18; ++r){
            float a = 0.f;
            #pragma unroll
            for (int j = 0; j < 18; ++j) a += Ainv18[r*18 + j] * rhs[j];
            orow[(r < 16) ? r : 29 + r] = f2bf(a);
        }
        int x = v % 48; int t2 = v / 48; int y = t2 % 48; int z = t2 / 48;
        short* base = c64 + (size_t)(z*48 + y)*3072;   // 8 groups * 48 * 8
        #pragma unroll
        for (int g = 0; g < 8; ++g)
            *(bf16x8*)(base + (size_t)(g*48 + x)*8) = *(const bf16x8*)&orow[g*8];
    }
}

// ---------------------------------------------------------------------------
// Kernel 5: conv1 3x3x3 (47->96) + bias + ReLU via bf16 MFMA.
// R7/R9 best shape: 1024 threads / 16 waves, tile 16x16x2 (grid.z = Mi/2).
// Wave map: 2 z-planes x 4 y-quads (4 rows each) x 2 OCH-HALVES — each
// b-fragment LDS read feeds 4 MFMAs, per-CU ds_read traffic halved at the
// SAME 16 waves/CU. (R10's 512-thr/16x16x1 regressed +18us/launch: weight
// staging amortization dominates, not grid fill.)
// 9 phases (dz,dy): weight slice dbuf in LDS, XOR swizzle.
// ---------------------------------------------------------------------------
__device__ __forceinline__ void stage_w(const short* __restrict__ src, short* dst, int tid){
    #pragma unroll
    for (int it = 0; it < 3; ++it){
        int d = (it*1024 + tid) * 16;
        if (d < 36864){
            bf16x8 v = *(const bf16x8*)((const char*)src + d);
            int ds = d ^ (((d >> 7) & 7) << 4);
            *(bf16x8*)((char*)dst + ds) = v;
        }
    }
}

__global__ __launch_bounds__(1024, 4) void conv1_mfma(const short* __restrict__ c64,
                                                      const short* __restrict__ wbf,
                                                      const float* __restrict__ b1,
                                                      short* __restrict__ h,
                                                      int Ni, int Mi){
    __shared__ short wlds[2][18432];
    const int tid = threadIdx.x;
    const int lane = tid & 63;
    const int wid  = tid >> 6;        // 0..15
    const int zw   = wid >> 3;        // 0..1   z-plane
    const int w4   = (wid >> 1) & 3;  // 0..3   y-quad (4 rows)
    const int th   = wid & 1;         // 0..1   och half
    const int l15 = lane & 15;
    const int lhi = lane >> 4;
    const int z0 = blockIdx.z * 2 + zw;
    const int x0 = blockIdx.x * 16;
    const int yw = blockIdx.y * 16 + w4 * 4;

    f32x4 acc[4][3];
    #pragma unroll
    for (int yr = 0; yr < 4; ++yr)
        #pragma unroll
        for (int t = 0; t < 3; ++t) acc[yr][t] = (f32x4){0.f,0.f,0.f,0.f};

    stage_w(wbf, &wlds[0][0], tid);

    const int grpstride = Ni*8;             // shorts per g-plane within (z,y)
    for (int p = 0; p < 9; ++p){
        __syncthreads();
        if (p < 8) stage_w(wbf + (size_t)(p+1)*18432, &wlds[(p+1)&1][0], tid);
        const char* wb = (const char*)&wlds[p&1][0];
        const int dz = p / 3;
        const int dy = p - dz*3;
        const int gzN = (z0 + dz)*Ni;

        #pragma unroll
        for (int dx = 0; dx < 3; ++dx){
            int gx = min(x0 + l15 + dx, Ni-1);
            const short* arow[4];
            #pragma unroll
            for (int yr = 0; yr < 4; ++yr){
                int gy = min(yw + yr + dy, Ni-1);
                arow[yr] = c64 + (size_t)(gzN + gy)*Ni*64 + (size_t)lhi*grpstride + gx*8;
            }
            #pragma unroll
            for (int kk = 0; kk < 2; ++kk){
                bf16x8 a0 = *(const bf16x8*)(arow[0] + kk*4*grpstride);
                bf16x8 a1 = *(const bf16x8*)(arow[1] + kk*4*grpstride);
                bf16x8 a2 = *(const bf16x8*)(arow[2] + kk*4*grpstride);
                bf16x8 a3 = *(const bf16x8*)(arow[3] + kk*4*grpstride);
                #pragma unroll
                for (int t = 0; t < 3; ++t){
                    int tt = th*3 + t;
                    int d = ((dx*96 + tt*16 + l15)*64 + kk*32 + lhi*8) * 2;
                    d ^= ((d >> 7) & 7) << 4;
                    bf16x8 b = *(const bf16x8*)(wb + d);
                    acc[0][t] = __builtin_amdgcn_mfma_f32_16x16x32_bf16(a0, b, acc[0][t], 0, 0, 0);
                    acc[1][t] = __builtin_amdgcn_mfma_f32_16x16x32_bf16(a1, b, acc[1][t], 0, 0, 0);
                    acc[2][t] = __builtin_amdgcn_mfma_f32_16x16x32_bf16(a2, b, acc[2][t], 0, 0, 0);
                    acc[3][t] = __builtin_amdgcn_mfma_f32_16x16x32_bf16(a3, b, acc[3][t], 0, 0, 0);
                }
            }
        }
    }

    #pragma unroll
    for (int yr = 0; yr < 4; ++yr){
        int yy = yw + yr;
        if (yy >= Mi) continue;
        #pragma unroll
        for (int t = 0; t < 3; ++t){
            int och = th*48 + t*16 + l15;
            float bias = b1[och];
            #pragma unroll
            for (int r = 0; r < 4; ++r){
                int xx = x0 + lhi*4 + r;
                if (xx < Mi){
                    size_t vo = ((size_t)(z0*Mi + yy)*Mi + xx)*NHID + och;
                    h[vo] = f2bf(fmaxf(acc[yr][t][r] + bias, 0.f));
                }
            }
        }
    }
}

// ---------------------------------------------------------------------------
// Kernel 6: fused MFMA conv2+ReLU -> conv3 -> gate -> rhs -> 47x47 solve.
// c64out / cin64 in x-interleaved layout; pad groups 6,7 written as zeros.
// bufA/bufB rows padded to 112 shorts (224B, 16B-aligned). conv3 output is
// written position-shifted (o>=47 -> o+1) so gate partner of k sits at 48+k:
// both gate operands become aligned bf16x8 LDS reads; cin64/AQ_Tb gathers
// become 16B/32B vector loads. rhsL at stride 64 (pad 48..63 zeroed).
// ---------------------------------------------------------------------------
__global__ __launch_bounds__(256) void cascade_mfma(const short* __restrict__ h,
                                                    const short* __restrict__ cin64,
                                                    const float* __restrict__ AQ_Tb,
                                                    const short* __restrict__ w2bf,
                                                    const float* __restrict__ b2,
                                                    const short* __restrict__ w3bf,
                                                    const float* __restrict__ b3,
                                                    const short* __restrict__ Ainvbf,
                                                    const float* __restrict__ dreg_p,
                                                    short* __restrict__ c64out,
                                                    float* __restrict__ fout,
                                                    int Mi, int off, int iter, int final_i){
    __shared__ short bufA[64][112];
    __shared__ short bufB[64][112];
    const int tid = threadIdx.x;
    const int lane = tid & 63;
    const int wv  = tid >> 6;
    const int l15 = lane & 15;
    const int lhi = lane >> 4;
    const int nvox = Mi*Mi*Mi;
    const int v0 = blockIdx.x * 64;
    const float dreg = dreg_p[0];

    for (int f = tid; f < 64*12; f += 256){
        int v = f / 12, c = f % 12;
        int gv = v0 + v;
        bf16x8 val = (bf16x8){0,0,0,0,0,0,0,0};
        if (gv < nvox) val = *(const bf16x8*)(h + (size_t)gv*NHID + c*8);
        *(bf16x8*)&bufA[v][c*8] = val;
    }
    __syncthreads();

    const int vox = wv*16 + l15;

    {   // conv2 + bias + ReLU -> bufB
        f32x4 acc2[6];
        #pragma unroll
        for (int m = 0; m < 6; ++m) acc2[m] = (f32x4){0.f,0.f,0.f,0.f};
        #pragma unroll
        for (int ks = 0; ks < 3; ++ks){
            bf16x8 bfr = *(const bf16x8*)&bufA[vox][lhi*8 + ks*32];
            #pragma unroll
            for (int m = 0; m < 6; ++m){
                bf16x8 a = *(const bf16x8*)(w2bf + (size_t)(m*16 + l15)*96 + lhi*8 + ks*32);
                acc2[m] = __builtin_amdgcn_mfma_f32_16x16x32_bf16(a, bfr, acc2[m], 0, 0, 0);
            }
        }
        #pragma unroll
        for (int m = 0; m < 6; ++m){
            int o0 = m*16 + lhi*4;
            float x0 = fmaxf(acc2[m][0] + b2[o0+0], 0.f);
            float x1 = fmaxf(acc2[m][1] + b2[o0+1], 0.f);
            float x2 = fmaxf(acc2[m][2] + b2[o0+2], 0.f);
            float x3 = fmaxf(acc2[m][3] + b2[o0+3], 0.f);
            *(unsigned*)&bufB[vox][o0]     = pk(f2bf(x0), f2bf(x1));
            *(unsigned*)&bufB[vox][o0 + 2] = pk(f2bf(x2), f2bf(x3));
        }
    }

    {   // conv3 + bias -> bufA (cc); wave-private rows, no barrier needed
        // positions shifted: och o stored at o + (o>=47)
        f32x4 acc3[6];
        #pragma unroll
        for (int m = 0; m < 6; ++m) acc3[m] = (f32x4){0.f,0.f,0.f,0.f};
        #pragma unroll
        for (int ks = 0; ks < 3; ++ks){
            bf16x8 bfr = *(const bf16x8*)&bufB[vox][lhi*8 + ks*32];
            #pragma unroll
            for (int m = 0; m < 6; ++m){
                bf16x8 a = *(const bf16x8*)(w3bf + (size_t)(m*16 + l15)*96 + lhi*8 + ks*32);
                acc3[m] = __builtin_amdgcn_mfma_f32_16x16x32_bf16(a, bfr, acc3[m], 0, 0, 0);
            }
        }
        #pragma unroll
        for (int m = 0; m < 6; ++m){
            int o0 = m*16 + lhi*4;
            float xv[4];
            #pragma unroll
            for (int e = 0; e < 4; ++e){
                int o = o0 + e;
                xv[e] = (o < 94) ? acc3[m][e] + b3[o] : 0.f;
            }
            if (o0 + 3 < 47){
                *(unsigned*)&bufA[vox][o0]     = pk(f2bf(xv[0]), f2bf(xv[1]));
                *(unsigned*)&bufA[vox][o0 + 2] = pk(f2bf(xv[2]), f2bf(xv[3]));
            } else {
                #pragma unroll
                for (int e = 0; e < 4; ++e){
                    int o = o0 + e;
                    bufA[vox][o + (o >= 47)] = f2bf(xv[e]);
                }
            }
        }
    }
    __syncthreads();

    short (*rhsL)[64] = (short(*)[64])&bufB[0][0];
    {   // gate + rhs (vectorized: bf16x8 cin/LDS reads, f32x4 AQ_Tb reads)
        int v = tid >> 2, q = tid & 3;
        int gv = v0 + v;
        int z = 0, y = 0, x = 0;
        bool live = (gv < nvox);
        if (live){
            z = gv / (Mi*Mi);
            int r = gv % (Mi*Mi);
            y = r / Mi; x = r % Mi;
        }
        const int Nin = Mi + 2;
        const size_t rbase = (size_t)((z+1)*Nin + (y+1))*Nin*64;
        const float* aqr = AQ_Tb + ((size_t)((z+off)*NFULL + (y+off))*NFULL + (x+off))*48;

        auto do_group = [&](int g){
            const int k0 = g*8;
            bf16x8 cc1 = *(const bf16x8*)&bufA[v][k0];
            bf16x8 cc2 = *(const bf16x8*)&bufA[v][48 + k0];
            bf16x8 cv = (bf16x8){0,0,0,0,0,0,0,0};
            if (iter > 0)
                cv = *(const bf16x8*)&cin64[rbase + (size_t)(g*Nin + (x+1))*8];
            f32x4 aq0 = *(const f32x4*)(aqr + k0);
            f32x4 aq1 = *(const f32x4*)(aqr + k0 + 4);
            short outs[8];
            #pragma unroll
            for (int j = 0; j < 8; ++j){
                int k = k0 + j;
                if (live && k < 47){
                    float gt = bf2f(cc1[j]) * sigmoidf(bf2f(cc2[j]));
                    if (iter > 0) gt += bf2f(cv[j]);
                    float aq = (j < 4) ? aq0[j] : aq1[j-4];
                    outs[j] = f2bf(aq + dreg * gt);
                } else outs[j] = 0;
            }
            *(bf16x8*)&rhsL[v][k0] = *(const bf16x8*)outs;
        };
        do_group(q);
        if (q < 2){
            do_group(q + 4);
        } else {
            // zero pad groups 6,7 (k 48..63) of the solve input
            *(bf16x8*)&rhsL[v][48 + (q - 2)*8] = (bf16x8){0,0,0,0,0,0,0,0};
        }
    }
    __syncthreads();

    {   // 47x47 solve
        f32x4 accS[3];
        #pragma unroll
        for (int m = 0; m < 3; ++m) accS[m] = (f32x4){0.f,0.f,0.f,0.f};
        #pragma unroll
        for (int ks = 0; ks < 2; ++ks){
            bf16x8 bfr = *(const bf16x8*)&rhsL[vox][lhi*8 + ks*32];
            #pragma unroll
            for (int m = 0; m < 3; ++m){
                bf16x8 a = *(const bf16x8*)(Ainvbf + (size_t)(m*16 + l15)*64 + lhi*8 + ks*32);
                accS[m] = __builtin_amdgcn_mfma_f32_16x16x32_bf16(a, bfr, accS[m], 0, 0, 0);
            }
        }
        int gv = v0 + vox;
        if (gv < nvox){
            if (final_i){
                #pragma unroll
                for (int m = 0; m < 3; ++m){
                    int k0 = m*16 + lhi*4;
                    #pragma unroll
                    for (int r = 0; r < 4; ++r){
                        int k = k0 + r;
                        if (k < 47) fout[(size_t)gv*NK + k] = accS[m][r];
                    }
                }
            } else {
                int z = gv / (Mi*Mi);
                int rr = gv % (Mi*Mi);
                int y = rr / Mi, x = rr % Mi;
                short* base = c64out + (size_t)(z*Mi + y)*Mi*64;
                #pragma unroll
                for (int m = 0; m < 3; ++m){
                    int k0 = m*16 + lhi*4;
                    int g = k0 >> 3, j = k0 & 7;
                    short s0 = f2bf(accS[m][0]);
                    short s1 = f2bf(accS[m][1]);
                    short s2 = f2bf(accS[m][2]);
                    short s3 = (k0 + 3 < 47) ? f2bf(accS[m][3]) : (short)0;
                    short* ad = base + (size_t)(g*Mi + x)*8 + j;
                    *(unsigned*)(ad)     = pk(s0, s1);
                    *(unsigned*)(ad + 2) = pk(s2, s3);
                }
            }
        }
    }

    if (!final_i){   // zero pad channels 48..63 (g-planes 6,7)
        for (int f = tid; f < 64*8; f += 256){
            int v = f >> 3, gv = v0 + v;
            if (gv < nvox){
                int u = f & 7;
                int c = 48 + u*2;
                int g = c >> 3, j = c & 7;
                int z = gv / (Mi*Mi);
                int rr = gv % (Mi*Mi);
                int y = rr / Mi, x = rr % Mi;
                *(unsigned*)&c64out[(size_t)(z*Mi + y)*Mi*64 + (size_t)(g*Mi + x)*8 + j] = 0;
            }
        }
    }
}

// ---------------------------------------------------------------------------
extern "C" void kernel_launch(void* const* d_in, const int* in_sizes, int n_in,
                              void* d_out, int out_size, void* d_ws, size_t ws_size,
                              hipStream_t stream){
    const float* b    = (const float*)d_in[0];
    const float* AQ   = (const float*)d_in[1];
    const float* w1   = (const float*)d_in[2];
    const float* b1   = (const float*)d_in[3];
    const float* w2   = (const float*)d_in[4];
    const float* b2   = (const float*)d_in[5];
    const float* w3   = (const float*)d_in[6];
    const float* b3   = (const float*)d_in[7];
    const float* dreg = (const float*)d_in[8];
    float* out = (float*)d_out;
    float* ws  = (float*)d_ws;

    const size_t NV48 = (size_t)48*48*48;                 // 110592
    float* Ainv18 = ws;                                    // 336
    float* AQ_Tb  = ws + 336;                              // NV48*48 (rows padded)
    short* hbuf   = (short*)(AQ_Tb + NV48*48);             // 46^3*96
    short* w1bf   = hbuf + (size_t)46*46*46*NHID;          // 4*27*96*64
    short* w2bf   = w1bf + (size_t)4*27*96*64;             // 4*96*96
    short* w3bf   = w2bf + (size_t)4*96*96;                // 4*96*96
    short* Ainvbf = w3bf + (size_t)4*96*96;                // 48*64
    short* Bseq   = Ainvbf + 48*64;                        // 30720
    short* c64A   = Bseq + 30720;                          // NV48*64 + slack
    short* c64B   = c64A + NV48*64 + 32768;

    prep_small<<<45, 256, 0, stream>>>(AQ, dreg, Ainv18, Ainvbf, Bseq,
                                       w1, w1bf, w2, w3, w2bf, w3bf);
    aqtb_mfma<<<(int)(NV48/64), 256, 0, stream>>>(b, Bseq, Ainv18, AQ_Tb, c64A);

    short* ccur = c64A;
    short* cnext = c64B;
    for (int i = 0; i < 4; ++i){
        int Ni = 48 - 2*i;
        int Mi = Ni - 2;
        dim3 g1((Mi + 15)/16, (Mi + 15)/16, Mi/2);
        conv1_mfma<<<g1, 1024, 0, stream>>>(ccur, w1bf + (size_t)i*27*96*64, b1 + i*96,
                                            hbuf, Ni, Mi);
        int nv = Mi*Mi*Mi;
        int fin = (i == 3) ? 1 : 0;
        cascade_mfma<<<(nv + 63)/64, 256, 0, stream>>>(
            hbuf, ccur, AQ_Tb, w2bf + (size_t)i*9216, b2 + i*96,
            w3bf + (size_t)i*9216, b3 + i*94, Ainvbf, dreg, cnext, out, Mi, i+1, i, fin);
        short* t = ccur; ccur = cnext; cnext = t;
    }
}

// Round 12
// 377.189 us; speedup vs baseline: 1.2330x; 1.0193x over previous
//
#include <hip/hip_runtime.h>
#include <math.h>

#define NS 300
#define NK 47
#define NHID 96
#define NFULL 48

typedef __attribute__((ext_vector_type(8))) short bf16x8;
typedef __attribute__((ext_vector_type(4))) float f32x4;
typedef __attribute__((ext_vector_type(4))) short s16x4;

__device__ __forceinline__ float sigmoidf(float x){ return 1.0f/(1.0f+expf(-x)); }
__device__ __forceinline__ short f2bf(float f){
    union { float f; unsigned u; } v; v.f = f;
    unsigned r = v.u + 0x7fffu + ((v.u >> 16) & 1u);
    return (short)(r >> 16);
}
__device__ __forceinline__ float bf2f(short s){
    union { unsigned u; float f; } v; v.u = ((unsigned)(unsigned short)s) << 16;
    return v.f;
}
__device__ __forceinline__ unsigned pk(short lo, short hi){
    return (unsigned)(unsigned short)lo | ((unsigned)(unsigned short)hi << 16);
}
// Bijective XCD swizzle: hardware block h (round-robin over 8 XCDs) ->
// logical id L such that each XCD owns a CONTIGUOUS logical chunk.
__device__ __forceinline__ int xcd_logical(int h, int nwg){
    int q = nwg >> 3, r = nwg & 7;
    int x = h & 7, s = h >> 3;
    return x*q + ((x < r) ? x : r) + s;
}

// c-tensor layout (all c64 buffers): addr(z,y,g,x,j) = ((z*N+y)*8+g)*N*8 + x*8 + j
//   g = ci>>3 (0..7), j = ci&7.  A 16-lane x-slice at fixed g is 256B contiguous.
// Groups 6,7 hold zeros — R4 semantics.
// AQ_Tb rows padded to 48 floats (192B, 16B-aligned) for vector loads.

// ---------------------------------------------------------------------------
// Kernel 1 (merged prologue): block 0 = AQT split-bf16 Gram47 + Newton-Schulz
// inverses (A47+dreg pad48, A18+0.01 pad32) + Bseq; blocks 1..41 = w1->bf16
// conversion; blocks 42..44 = w2/w3->bf16.
// ---------------------------------------------------------------------------
#define AQP 328
#define P47 72
#define P18 40
__global__ __launch_bounds__(256) void prep_small(const float* __restrict__ AQ,
                           const float* __restrict__ dreg_p,
                           float* __restrict__ Ainv18, short* __restrict__ Ainvbf,
                           short* __restrict__ Bseq,
                           const float* __restrict__ w1, short* __restrict__ w1bf,
                           const float* __restrict__ w2, const float* __restrict__ w3,
                           short* __restrict__ w2bf, short* __restrict__ w3bf){
    __shared__ __align__(16) char smem[93824];

    const int tid = threadIdx.x;
    const int blk = blockIdx.x;

    if (blk >= 1){
        if (blk <= 41){
            int idx = (blk - 1)*256 + tid;
            if (idx < 4*27*96){
                int o = idx % 96; int rest = idx / 96; int s = rest % 27; int i = rest / 27;
                const float* src = w1 + ((size_t)i*96 + o)*1269 + s;
                short* dst = w1bf + (size_t)idx*64;
                #pragma unroll
                for (int ci = 0; ci < 47; ++ci) dst[ci] = f2bf(src[ci*27]);
                #pragma unroll
                for (int ci = 47; ci < 64; ++ci) dst[ci] = 0;
            }
        } else {
            int idx = (blk - 42)*256 + tid;
            if (idx < 768){
                if (idx < 384){
                    const float* src = w2 + (size_t)idx*96;
                    short* dst = w2bf + (size_t)idx*96;
                    for (int k = 0; k < 96; ++k) dst[k] = f2bf(src[k]);
                } else {
                    int j = idx - 384;
                    int i = j / 96, o = j % 96;
                    short* dst = w3bf + (size_t)j*96;
                    if (o < 94){
                        const float* src = w3 + ((size_t)i*94 + o)*96;
                        for (int k = 0; k < 96; ++k) dst[k] = f2bf(src[k]);
                    } else {
                        for (int k = 0; k < 96; ++k) dst[k] = 0;
                    }
                }
            }
        }
        return;
    }

    short* AQh = (short*)smem;
    short* AQl = AQh + 48*AQP;
    float* Gf  = (float*)(smem + 62976);
    short* M47 = (short*)smem;
    short* M18 = (short*)(smem + 72960);
    float* rs47 = (float*)(smem + 93440);
    float* rs18 = rs47 + 48;
    float* shc  = rs18 + 32;

    const int lane = tid & 63;
    const int wv  = tid >> 6;
    const int l15 = lane & 15;
    const int lhi = lane >> 4;
    const float dreg = dreg_p[0];

    #pragma unroll 4
    for (int idx = tid; idx < 48*AQP; idx += 256){
        int k = idx / AQP, n = idx - k*AQP;
        float a = (k < 47 && n < 300) ? AQ[n*NK + k] : 0.f;
        short h = f2bf(a);
        short l = f2bf(a - bf2f(h));
        AQh[idx] = h; AQl[idx] = l;
        if (n < 320){
            int step = n >> 5, lh = (n >> 3) & 3, j = n & 7;
            int t = k >> 4, kl = k & 15;
            int base = ((step*3 + t)*2)*512 + (lh*16 + kl)*8 + j;
            Bseq[base]       = h;
            Bseq[base + 512] = l;
        }
    }
    __syncthreads();

    const int t0 = wv, t1 = wv + 4, t2 = wv + 8;
    f32x4 g0, g1, g2;
    {
        auto gram = [&](int t) -> f32x4 {
            int tt = (t < 9) ? t : t - 9;
            int k0 = (tt/3)*16, l0 = (tt%3)*16;
            f32x4 a = (f32x4){0.f,0.f,0.f,0.f};
            for (int ks = 0; ks < 10; ++ks){
                int off = ks*32 + lhi*8;
                bf16x8 ph = *(const bf16x8*)&AQh[(k0+l15)*AQP + off];
                bf16x8 pl = *(const bf16x8*)&AQl[(k0+l15)*AQP + off];
                bf16x8 qh = *(const bf16x8*)&AQh[(l0+l15)*AQP + off];
                bf16x8 ql = *(const bf16x8*)&AQl[(l0+l15)*AQP + off];
                a = __builtin_amdgcn_mfma_f32_16x16x32_bf16(ph, qh, a, 0,0,0);
                a = __builtin_amdgcn_mfma_f32_16x16x32_bf16(pl, qh, a, 0,0,0);
                a = __builtin_amdgcn_mfma_f32_16x16x32_bf16(ph, ql, a, 0,0,0);
            }
            return a;
        };
        g0 = gram(t0); g1 = gram(t1); g2 = gram(t2);
    }
    __syncthreads();

    for (int i = tid; i < 8*48*P47; i += 256) M47[i] = 0;
    for (int i = tid; i < 8*32*P18; i += 256) M18[i] = 0;
    {
        auto wrG = [&](int t, f32x4 a){
            if (t < 9){
                int k0 = (t/3)*16, l0 = (t%3)*16;
                #pragma unroll
                for (int r = 0; r < 4; ++r)
                    Gf[(k0 + lhi*4 + r)*52 + (l0 + l15)] = a[r];
            }
        };
        wrG(t0,g0); wrG(t1,g1); wrG(t2,g2);
    }
    __syncthreads();

    short* Ah  = M47;            short* Al  = M47 + 3456;
    short* Xah = M47 + 2*3456;   short* Xal = M47 + 3*3456;
    short* Xbh = M47 + 4*3456;   short* Xbl = M47 + 5*3456;
    short* Zh  = M47 + 6*3456;   short* Zl  = M47 + 7*3456;
    short* Bh8 = M18;            short* Bl8 = M18 + 1280;
    short* Xah8= M18 + 2*1280;   short* Xal8= M18 + 3*1280;
    short* Xbh8= M18 + 4*1280;   short* Xbl8= M18 + 5*1280;
    short* Zh8 = M18 + 6*1280;   short* Zl8 = M18 + 7*1280;

    {
        auto wrA = [&](int t, f32x4 a){
            if (t < 9){
                int k0 = (t/3)*16, l0 = (t%3)*16;
                #pragma unroll
                for (int r = 0; r < 4; ++r){
                    int k = k0 + lhi*4 + r, l = l0 + l15;
                    float v = (k < 47 && l < 47) ? a[r] + (k==l ? dreg : 0.f)
                                                 : ((k==l) ? 1.f : 0.f);
                    short h = f2bf(v);
                    Ah[k*P47 + l] = h;
                    Al[k*P47 + l] = f2bf(v - bf2f(h));
                }
            }
        };
        wrA(t0,g0); wrA(t1,g1); wrA(t2,g2);
    }
    if (tid < 48){
        float s = 1.f;
        if (tid < 47){
            s = dreg;
            for (int l = 0; l < 47; ++l) s += fabsf(Gf[tid*52 + l]);
        }
        rs47[tid] = s;
    }
    if (tid >= 64 && tid < 96){
        int r = tid - 64;
        float s = 1.f;
        if (r < 18){
            int gk = (r < 16) ? r : r + 29;
            s = 0.f;
            for (int l = 0; l < 18; ++l){
                int gl = (l < 16) ? l : l + 29;
                s += fabsf(Gf[gk*52 + gl] + ((l==r) ? 0.01f : 0.f));
            }
        }
        rs18[r] = s;
    }
    for (int e = tid; e < 32*32; e += 256){
        int k = e >> 5, l = e & 31;
        float v;
        if (k < 18 && l < 18){
            int gk = (k < 16) ? k : k + 29;
            int gl = (l < 16) ? l : l + 29;
            v = Gf[gk*52 + gl] + ((k==l) ? 0.01f : 0.f);
        } else v = (k==l) ? 1.f : 0.f;
        short h = f2bf(v);
        Bh8[k*P18 + l] = h;
        Bl8[k*P18 + l] = f2bf(v - bf2f(h));
    }
    __syncthreads();

    if (tid == 0){
        float m = 0.f;
        for (int i = 0; i < 48; ++i) m = fmaxf(m, rs47[i]);
        shc[0] = 1.f / m;
    }
    if (tid == 1){
        float m = 0.f;
        for (int i = 0; i < 32; ++i) m = fmaxf(m, rs18[i]);
        shc[1] = 1.f / m;
    }
    __syncthreads();

    if (tid < 48){
        float c = shc[0];
        short h = f2bf(c);
        Xah[tid*P47 + tid] = h;
        Xal[tid*P47 + tid] = f2bf(c - bf2f(h));
    } else if (tid >= 64 && tid < 96){
        int r = tid - 64;
        float c = shc[1];
        short h = f2bf(c);
        Xah8[r*P18 + r] = h;
        Xal8[r*P18 + r] = f2bf(c - bf2f(h));
    }
    __syncthreads();

    auto mmT = [&](int t, const short* Ph, const short* Pl,
                   const short* Qh, const short* Ql) -> f32x4 {
        int tt = (t < 9) ? t : t - 9;
        int k0 = (tt/3)*16, l0 = (tt%3)*16;
        f32x4 a = (f32x4){0.f,0.f,0.f,0.f};
        #pragma unroll
        for (int kk = 0; kk < 2; ++kk){
            int off = kk*32 + lhi*8;
            bf16x8 ph = *(const bf16x8*)&Ph[(k0+l15)*P47 + off];
            bf16x8 pl = *(const bf16x8*)&Pl[(k0+l15)*P47 + off];
            bf16x8 qh = *(const bf16x8*)&Qh[(l0+l15)*P47 + off];
            bf16x8 ql = *(const bf16x8*)&Ql[(l0+l15)*P47 + off];
            a = __builtin_amdgcn_mfma_f32_16x16x32_bf16(ph, qh, a, 0,0,0);
            a = __builtin_amdgcn_mfma_f32_16x16x32_bf16(pl, qh, a, 0,0,0);
            a = __builtin_amdgcn_mfma_f32_16x16x32_bf16(ph, ql, a, 0,0,0);
        }
        return a;
    };
    auto mm8 = [&](const short* Ph, const short* Pl,
                   const short* Qh, const short* Ql) -> f32x4 {
        int k0 = (wv >> 1)*16, l0 = (wv & 1)*16;
        int off = lhi*8;
        bf16x8 ph = *(const bf16x8*)&Ph[(k0+l15)*P18 + off];
        bf16x8 pl = *(const bf16x8*)&Pl[(k0+l15)*P18 + off];
        bf16x8 qh = *(const bf16x8*)&Qh[(l0+l15)*P18 + off];
        bf16x8 ql = *(const bf16x8*)&Ql[(l0+l15)*P18 + off];
        f32x4 a = (f32x4){0.f,0.f,0.f,0.f};
        a = __builtin_amdgcn_mfma_f32_16x16x32_bf16(ph, qh, a, 0,0,0);
        a = __builtin_amdgcn_mfma_f32_16x16x32_bf16(pl, qh, a, 0,0,0);
        a = __builtin_amdgcn_mfma_f32_16x16x32_bf16(ph, ql, a, 0,0,0);
        return a;
    };

    short *Xch = Xah, *Xcl = Xal, *Xnh = Xbh, *Xnl = Xbl;
    short *Xch8 = Xah8, *Xcl8 = Xal8, *Xnh8 = Xbh8, *Xnl8 = Xbl8;

    for (int it = 0; it < 10; ++it){
        f32x4 y0 = mmT(t0, Ah, Al, Xch, Xcl);
        f32x4 y1 = mmT(t1, Ah, Al, Xch, Xcl);
        f32x4 y2 = mmT(t2, Ah, Al, Xch, Xcl);
        f32x4 y8 = mm8(Bh8, Bl8, Xch8, Xcl8);
        auto wrZ = [&](int t, f32x4 a){
            if (t < 9){
                int k0 = (t/3)*16, l0 = (t%3)*16;
                #pragma unroll
                for (int r = 0; r < 4; ++r){
                    int k = k0 + lhi*4 + r, l = l0 + l15;
                    float z = ((k==l) ? 2.f : 0.f) - a[r];
                    short h = f2bf(z);
                    Zh[k*P47 + l] = h;
                    Zl[k*P47 + l] = f2bf(z - bf2f(h));
                }
            }
        };
        wrZ(t0,y0); wrZ(t1,y1); wrZ(t2,y2);
        {
            int k0 = (wv >> 1)*16, l0 = (wv & 1)*16;
            #pragma unroll
            for (int r = 0; r < 4; ++r){
                int k = k0 + lhi*4 + r, l = l0 + l15;
                float z = ((k==l) ? 2.f : 0.f) - y8[r];
                short h = f2bf(z);
                Zh8[k*P18 + l] = h;
                Zl8[k*P18 + l] = f2bf(z - bf2f(h));
            }
        }
        __syncthreads();
        f32x4 x0 = mmT(t0, Xch, Xcl, Zh, Zl);
        f32x4 x1 = mmT(t1, Xch, Xcl, Zh, Zl);
        f32x4 x2 = mmT(t2, Xch, Xcl, Zh, Zl);
        f32x4 x8 = mm8(Xch8, Xcl8, Zh8, Zl8);
        if (it < 9){
            auto wrX = [&](int t, f32x4 a){
                if (t < 9){
                    int k0 = (t/3)*16, l0 = (t%3)*16;
                    #pragma unroll
                    for (int r = 0; r < 4; ++r){
                        int k = k0 + lhi*4 + r, l = l0 + l15;
                        short h = f2bf(a[r]);
                        Xnh[k*P47 + l] = h;
                        Xnl[k*P47 + l] = f2bf(a[r] - bf2f(h));
                    }
                }
            };
            wrX(t0,x0); wrX(t1,x1); wrX(t2,x2);
            int k0 = (wv >> 1)*16, l0 = (wv & 1)*16;
            #pragma unroll
            for (int r = 0; r < 4; ++r){
                int k = k0 + lhi*4 + r, l = l0 + l15;
                short h = f2bf(x8[r]);
                Xnh8[k*P18 + l] = h;
                Xnl8[k*P18 + l] = f2bf(x8[r] - bf2f(h));
            }
        } else {
            auto wrF = [&](int t, f32x4 a){
                if (t < 9){
                    int k0 = (t/3)*16, l0 = (t%3)*16;
                    #pragma unroll
                    for (int r = 0; r < 4; ++r){
                        int k = k0 + lhi*4 + r, l = l0 + l15;
                        float v = (k < 47 && l < 47) ? a[r] : 0.f;
                        Ainvbf[k*64 + l] = f2bf(v);
                    }
                }
            };
            wrF(t0,x0); wrF(t1,x1); wrF(t2,x2);
            int k0 = (wv >> 1)*16, l0 = (wv & 1)*16;
            #pragma unroll
            for (int r = 0; r < 4; ++r){
                int k = k0 + lhi*4 + r, l = l0 + l15;
                if (k < 18 && l < 18) Ainv18[k*18 + l] = x8[r];
            }
        }
        __syncthreads();
        short* tp;
        tp = Xch; Xch = Xnh; Xnh = tp;
        tp = Xcl; Xcl = Xnl; Xnl = tp;
        tp = Xch8; Xch8 = Xnh8; Xnh8 = tp;
        tp = Xcl8; Xcl8 = Xnl8; Xnl8 = tp;
    }

    for (int e = tid; e < 48*16; e += 256){
        int k = e >> 4, j = e & 15;
        Ainvbf[k*64 + 48 + j] = 0;
    }
}

// ---------------------------------------------------------------------------
// Kernel 2 (FUSED aqtb + init_c): AQ_Tb = b @ AQ via split-bf16 MFMA with
// LDS-staged coalesced b loads (double-buffered, rows padded to 36 floats),
// then the 18x18 init solve runs in-block on the fresh accumulators.
// ---------------------------------------------------------------------------
__global__ __launch_bounds__(256) void aqtb_mfma(const float* __restrict__ b,
                                                 const short* __restrict__ Bseq,
                                                 const float* __restrict__ Ainv18,
                                                 float* __restrict__ AQ_Tb,
                                                 short* __restrict__ c64){
    __shared__ float blds[2][64][36];
    const int tid  = threadIdx.x;
    const int lane = tid & 63;
    const int wv   = tid >> 6;
    const int l15  = lane & 15;
    const int lhi  = lane >> 4;
    const int v0   = blockIdx.x*64;
    const int srow = tid >> 2;          // 0..63: staging row
    const int schk = (tid & 3)*8;       // 0,8,16,24: staging chunk
    const float* bsrc = b + (size_t)(v0 + srow)*NS;
    const short* bs = Bseq + lane*8;

    auto stage = [&](int s, int buf){
        int n0 = s*32 + schk;
        float* dst = &blds[buf][srow][schk];
        if (n0 + 8 <= NS){
            *(f32x4*)dst       = *(const f32x4*)(bsrc + n0);
            *(f32x4*)(dst + 4) = *(const f32x4*)(bsrc + n0 + 4);
        } else {
            #pragma unroll
            for (int j = 0; j < 8; ++j){
                int n = n0 + j;
                dst[j] = (n < NS) ? bsrc[n] : 0.f;
            }
        }
    };

    f32x4 acc[3];
    #pragma unroll
    for (int t = 0; t < 3; ++t) acc[t] = (f32x4){0.f,0.f,0.f,0.f};

    const int arow = wv*16 + l15;       // this thread's MFMA A row
    stage(0, 0);

    for (int step = 0; step < 10; ++step){
        __syncthreads();
        if (step + 1 < 10) stage(step + 1, (step + 1) & 1);
        const float* src = &blds[step & 1][arow][lhi*8];
        f32x4 q0 = *(const f32x4*)src;
        f32x4 q1 = *(const f32x4*)(src + 4);

        bf16x8 Ah, Al;
        #pragma unroll
        for (int j = 0; j < 4; ++j){
            short h0 = f2bf(q0[j]);
            Ah[j] = h0;
            Al[j] = f2bf(q0[j] - bf2f(h0));
            short h1 = f2bf(q1[j]);
            Ah[4 + j] = h1;
            Al[4 + j] = f2bf(q1[j] - bf2f(h1));
        }
        const short* bstep = bs + step*3072;
        #pragma unroll
        for (int t = 0; t < 3; ++t){
            bf16x8 Bh = *(const bf16x8*)(bstep + t*1024);
            bf16x8 Bl = *(const bf16x8*)(bstep + t*1024 + 512);
            acc[t] = __builtin_amdgcn_mfma_f32_16x16x32_bf16(Ah, Bh, acc[t], 0, 0, 0);
            acc[t] = __builtin_amdgcn_mfma_f32_16x16x32_bf16(Al, Bh, acc[t], 0, 0, 0);
            acc[t] = __builtin_amdgcn_mfma_f32_16x16x32_bf16(Ah, Bl, acc[t], 0, 0, 0);
        }
    }

    // ---- global AQ_Tb store (unchanged layout) ----
    const int vbase = v0 + wv*16 + lhi*4;
    #pragma unroll
    for (int t = 0; t < 3; ++t){
        int k = t*16 + l15;
        if (k < NK){
            #pragma unroll
            for (int r = 0; r < 4; ++r)
                AQ_Tb[(size_t)(vbase + r)*48 + k] = acc[t][r];
        }
    }

    // ---- fused init_c: dump acc -> LDS (overlay b-staging), solve 18x18 ----
    __syncthreads();                       // blds dead after step 9
    float* sol = &blds[0][0][0];           // 64 rows x 48 floats = 12288B
    #pragma unroll
    for (int t = 0; t < 3; ++t){
        int k = t*16 + l15;
        if (k < NK){
            #pragma unroll
            for (int r = 0; r < 4; ++r)
                sol[(wv*16 + lhi*4 + r)*48 + k] = acc[t][r];
        }
    }
    __syncthreads();

    if (tid < 64){
        int v = v0 + tid;
        const float* row = sol + tid*48;
        float rhs[18];
        #pragma unroll
        for (int j = 0; j < 16; ++j) rhs[j] = row[j];
        rhs[16] = row[45];
        rhs[17] = row[46];
        short orow[64];
        #pragma unroll
        for (int k = 0; k < 64; ++k) orow[k] = 0;
        #pragma unroll
        for (int r = 0; r < 18; ++r){
            float a = 0.f;
            #pragma unroll
            for (int j = 0; j < 18; ++j) a += Ainv18[r*18 + j] * rhs[j];
            orow[(r < 16) ? r : 29 + r] = f2bf(a);
        }
        int x = v % 48; int t2 = v / 48; int y = t2 % 48; int z = t2 / 48;
        short* base = c64 + (size_t)(z*48 + y)*3072;   // 8 groups * 48 * 8
        #pragma unroll
        for (int g = 0; g < 8; ++g)
            *(bf16x8*)(base + (size_t)(g*48 + x)*8) = *(const bf16x8*)&orow[g*8];
    }
}

// ---------------------------------------------------------------------------
// Kernel 5: conv1 3x3x3 (47->96) + bias + ReLU via bf16 MFMA.
// R7/R9 best shape: 1024 threads / 16 waves, 16x16x2 tile. 1D grid with
// XCD-aware remap: each XCD gets a contiguous z-major chunk so halo reads
// hit its private L2 (z-slab of c64 ~1.9MB < 4MB/XCD).
// 9 phases (dz,dy): weight slice dbuf in LDS, XOR swizzle.
// ---------------------------------------------------------------------------
__device__ __forceinline__ void stage_w(const short* __restrict__ src, short* dst, int tid){
    #pragma unroll
    for (int it = 0; it < 3; ++it){
        int d = (it*1024 + tid) * 16;
        if (d < 36864){
            bf16x8 v = *(const bf16x8*)((const char*)src + d);
            int ds = d ^ (((d >> 7) & 7) << 4);
            *(bf16x8*)((char*)dst + ds) = v;
        }
    }
}

__global__ __launch_bounds__(1024, 4) void conv1_mfma(const short* __restrict__ c64,
                                                      const short* __restrict__ wbf,
                                                      const float* __restrict__ b1,
                                                      short* __restrict__ h,
                                                      int Ni, int Mi, int nxy){
    __shared__ short wlds[2][18432];
    const int tid = threadIdx.x;
    const int lane = tid & 63;
    const int wid  = tid >> 6;        // 0..15
    const int zw   = wid >> 3;        // 0..1   z-plane
    const int w4   = (wid >> 1) & 3;  // 0..3   y-quad (4 rows)
    const int th   = wid & 1;         // 0..1   och half
    const int l15 = lane & 15;
    const int lhi = lane >> 4;

    const int L = xcd_logical(blockIdx.x, gridDim.x);
    const int bz = L / nxy;
    const int rxy = L - bz*nxy;
    const int nbx = (Mi + 15) >> 4;
    const int by = rxy / nbx;
    const int bx = rxy - by*nbx;

    const int z0 = bz * 2 + zw;
    const int x0 = bx * 16;
    const int yw = by * 16 + w4 * 4;

    f32x4 acc[4][3];
    #pragma unroll
    for (int yr = 0; yr < 4; ++yr)
        #pragma unroll
        for (int t = 0; t < 3; ++t) acc[yr][t] = (f32x4){0.f,0.f,0.f,0.f};

    stage_w(wbf, &wlds[0][0], tid);

    const int grpstride = Ni*8;             // shorts per g-plane within (z,y)
    for (int p = 0; p < 9; ++p){
        __syncthreads();
        if (p < 8) stage_w(wbf + (size_t)(p+1)*18432, &wlds[(p+1)&1][0], tid);
        const char* wb = (const char*)&wlds[p&1][0];
        const int dz = p / 3;
        const int dy = p - dz*3;
        const int gzN = (z0 + dz)*Ni;

        #pragma unroll
        for (int dx = 0; dx < 3; ++dx){
            int gx = min(x0 + l15 + dx, Ni-1);
            const short* arow[4];
            #pragma unroll
            for (int yr = 0; yr < 4; ++yr){
                int gy = min(yw + yr + dy, Ni-1);
                arow[yr] = c64 + (size_t)(gzN + gy)*Ni*64 + (size_t)lhi*grpstride + gx*8;
            }
            #pragma unroll
            for (int kk = 0; kk < 2; ++kk){
                bf16x8 a0 = *(const bf16x8*)(arow[0] + kk*4*grpstride);
                bf16x8 a1 = *(const bf16x8*)(arow[1] + kk*4*grpstride);
                bf16x8 a2 = *(const bf16x8*)(arow[2] + kk*4*grpstride);
                bf16x8 a3 = *(const bf16x8*)(arow[3] + kk*4*grpstride);
                #pragma unroll
                for (int t = 0; t < 3; ++t){
                    int tt = th*3 + t;
                    int d = ((dx*96 + tt*16 + l15)*64 + kk*32 + lhi*8) * 2;
                    d ^= ((d >> 7) & 7) << 4;
                    bf16x8 b = *(const bf16x8*)(wb + d);
                    acc[0][t] = __builtin_amdgcn_mfma_f32_16x16x32_bf16(a0, b, acc[0][t], 0, 0, 0);
                    acc[1][t] = __builtin_amdgcn_mfma_f32_16x16x32_bf16(a1, b, acc[1][t], 0, 0, 0);
                    acc[2][t] = __builtin_amdgcn_mfma_f32_16x16x32_bf16(a2, b, acc[2][t], 0, 0, 0);
                    acc[3][t] = __builtin_amdgcn_mfma_f32_16x16x32_bf16(a3, b, acc[3][t], 0, 0, 0);
                }
            }
        }
    }

    #pragma unroll
    for (int yr = 0; yr < 4; ++yr){
        int yy = yw + yr;
        if (yy >= Mi) continue;
        #pragma unroll
        for (int t = 0; t < 3; ++t){
            int och = th*48 + t*16 + l15;
            float bias = b1[och];
            #pragma unroll
            for (int r = 0; r < 4; ++r){
                int xx = x0 + lhi*4 + r;
                if (xx < Mi){
                    size_t vo = ((size_t)(z0*Mi + yy)*Mi + xx)*NHID + och;
                    h[vo] = f2bf(fmaxf(acc[yr][t][r] + bias, 0.f));
                }
            }
        }
    }
}

// ---------------------------------------------------------------------------
// Kernel 6: fused MFMA conv2+ReLU -> conv3 -> gate -> rhs -> 47x47 solve.
// XCD-swizzled 1D grid (contiguous voxel chunks per XCD for cin64/AQ_Tb L2
// locality). Otherwise identical to R11.
// ---------------------------------------------------------------------------
__global__ __launch_bounds__(256) void cascade_mfma(const short* __restrict__ h,
                                                    const short* __restrict__ cin64,
                                                    const float* __restrict__ AQ_Tb,
                                                    const short* __restrict__ w2bf,
                                                    const float* __restrict__ b2,
                                                    const short* __restrict__ w3bf,
                                                    const float* __restrict__ b3,
                                                    const short* __restrict__ Ainvbf,
                                                    const float* __restrict__ dreg_p,
                                                    short* __restrict__ c64out,
                                                    float* __restrict__ fout,
                                                    int Mi, int off, int iter, int final_i){
    __shared__ short bufA[64][112];
    __shared__ short bufB[64][112];
    const int tid = threadIdx.x;
    const int lane = tid & 63;
    const int wv  = tid >> 6;
    const int l15 = lane & 15;
    const int lhi = lane >> 4;
    const int nvox = Mi*Mi*Mi;
    const int v0 = xcd_logical(blockIdx.x, gridDim.x) * 64;
    const float dreg = dreg_p[0];

    for (int f = tid; f < 64*12; f += 256){
        int v = f / 12, c = f % 12;
        int gv = v0 + v;
        bf16x8 val = (bf16x8){0,0,0,0,0,0,0,0};
        if (gv < nvox) val = *(const bf16x8*)(h + (size_t)gv*NHID + c*8);
        *(bf16x8*)&bufA[v][c*8] = val;
    }
    __syncthreads();

    const int vox = wv*16 + l15;

    {   // conv2 + bias + ReLU -> bufB
        f32x4 acc2[6];
        #pragma unroll
        for (int m = 0; m < 6; ++m) acc2[m] = (f32x4){0.f,0.f,0.f,0.f};
        #pragma unroll
        for (int ks = 0; ks < 3; ++ks){
            bf16x8 bfr = *(const bf16x8*)&bufA[vox][lhi*8 + ks*32];
            #pragma unroll
            for (int m = 0; m < 6; ++m){
                bf16x8 a = *(const bf16x8*)(w2bf + (size_t)(m*16 + l15)*96 + lhi*8 + ks*32);
                acc2[m] = __builtin_amdgcn_mfma_f32_16x16x32_bf16(a, bfr, acc2[m], 0, 0, 0);
            }
        }
        #pragma unroll
        for (int m = 0; m < 6; ++m){
            int o0 = m*16 + lhi*4;
            float x0 = fmaxf(acc2[m][0] + b2[o0+0], 0.f);
            float x1 = fmaxf(acc2[m][1] + b2[o0+1], 0.f);
            float x2 = fmaxf(acc2[m][2] + b2[o0+2], 0.f);
            float x3 = fmaxf(acc2[m][3] + b2[o0+3], 0.f);
            *(unsigned*)&bufB[vox][o0]     = pk(f2bf(x0), f2bf(x1));
            *(unsigned*)&bufB[vox][o0 + 2] = pk(f2bf(x2), f2bf(x3));
        }
    }

    {   // conv3 + bias -> bufA (cc); wave-private rows, no barrier needed
        // positions shifted: och o stored at o + (o>=47)
        f32x4 acc3[6];
        #pragma unroll
        for (int m = 0; m < 6; ++m) acc3[m] = (f32x4){0.f,0.f,0.f,0.f};
        #pragma unroll
        for (int ks = 0; ks < 3; ++ks){
            bf16x8 bfr = *(const bf16x8*)&bufB[vox][lhi*8 + ks*32];
            #pragma unroll
            for (int m = 0; m < 6; ++m){
                bf16x8 a = *(const bf16x8*)(w3bf + (size_t)(m*16 + l15)*96 + lhi*8 + ks*32);
                acc3[m] = __builtin_amdgcn_mfma_f32_16x16x32_bf16(a, bfr, acc3[m], 0, 0, 0);
            }
        }
        #pragma unroll
        for (int m = 0; m < 6; ++m){
            int o0 = m*16 + lhi*4;
            float xv[4];
            #pragma unroll
            for (int e = 0; e < 4; ++e){
                int o = o0 + e;
                xv[e] = (o < 94) ? acc3[m][e] + b3[o] : 0.f;
            }
            if (o0 + 3 < 47){
                *(unsigned*)&bufA[vox][o0]     = pk(f2bf(xv[0]), f2bf(xv[1]));
                *(unsigned*)&bufA[vox][o0 + 2] = pk(f2bf(xv[2]), f2bf(xv[3]));
            } else {
                #pragma unroll
                for (int e = 0; e < 4; ++e){
                    int o = o0 + e;
                    bufA[vox][o + (o >= 47)] = f2bf(xv[e]);
                }
            }
        }
    }
    __syncthreads();

    short (*rhsL)[64] = (short(*)[64])&bufB[0][0];
    {   // gate + rhs (vectorized: bf16x8 cin/LDS reads, f32x4 AQ_Tb reads)
        int v = tid >> 2, q = tid & 3;
        int gv = v0 + v;
        int z = 0, y = 0, x = 0;
        bool live = (gv < nvox);
        if (live){
            z = gv / (Mi*Mi);
            int r = gv % (Mi*Mi);
            y = r / Mi; x = r % Mi;
        }
        const int Nin = Mi + 2;
        const size_t rbase = (size_t)((z+1)*Nin + (y+1))*Nin*64;
        const float* aqr = AQ_Tb + ((size_t)((z+off)*NFULL + (y+off))*NFULL + (x+off))*48;

        auto do_group = [&](int g){
            const int k0 = g*8;
            bf16x8 cc1 = *(const bf16x8*)&bufA[v][k0];
            bf16x8 cc2 = *(const bf16x8*)&bufA[v][48 + k0];
            bf16x8 cv = (bf16x8){0,0,0,0,0,0,0,0};
            if (iter > 0)
                cv = *(const bf16x8*)&cin64[rbase + (size_t)(g*Nin + (x+1))*8];
            f32x4 aq0 = *(const f32x4*)(aqr + k0);
            f32x4 aq1 = *(const f32x4*)(aqr + k0 + 4);
            short outs[8];
            #pragma unroll
            for (int j = 0; j < 8; ++j){
                int k = k0 + j;
                if (live && k < 47){
                    float gt = bf2f(cc1[j]) * sigmoidf(bf2f(cc2[j]));
                    if (iter > 0) gt += bf2f(cv[j]);
                    float aq = (j < 4) ? aq0[j] : aq1[j-4];
                    outs[j] = f2bf(aq + dreg * gt);
                } else outs[j] = 0;
            }
            *(bf16x8*)&rhsL[v][k0] = *(const bf16x8*)outs;
        };
        do_group(q);
        if (q < 2){
            do_group(q + 4);
        } else {
            // zero pad groups 6,7 (k 48..63) of the solve input
            *(bf16x8*)&rhsL[v][48 + (q - 2)*8] = (bf16x8){0,0,0,0,0,0,0,0};
        }
    }
    __syncthreads();

    {   // 47x47 solve
        f32x4 accS[3];
        #pragma unroll
        for (int m = 0; m < 3; ++m) accS[m] = (f32x4){0.f,0.f,0.f,0.f};
        #pragma unroll
        for (int ks = 0; ks < 2; ++ks){
            bf16x8 bfr = *(const bf16x8*)&rhsL[vox][lhi*8 + ks*32];
            #pragma unroll
            for (int m = 0; m < 3; ++m){
                bf16x8 a = *(const bf16x8*)(Ainvbf + (size_t)(m*16 + l15)*64 + lhi*8 + ks*32);
                accS[m] = __builtin_amdgcn_mfma_f32_16x16x32_bf16(a, bfr, accS[m], 0, 0, 0);
            }
        }
        int gv = v0 + vox;
        if (gv < nvox){
            if (final_i){
                #pragma unroll
                for (int m = 0; m < 3; ++m){
                    int k0 = m*16 + lhi*4;
                    #pragma unroll
                    for (int r = 0; r < 4; ++r){
                        int k = k0 + r;
                        if (k < 47) fout[(size_t)gv*NK + k] = accS[m][r];
                    }
                }
            } else {
                int z = gv / (Mi*Mi);
                int rr = gv % (Mi*Mi);
                int y = rr / Mi, x = rr % Mi;
                short* base = c64out + (size_t)(z*Mi + y)*Mi*64;
                #pragma unroll
                for (int m = 0; m < 3; ++m){
                    int k0 = m*16 + lhi*4;
                    int g = k0 >> 3, j = k0 & 7;
                    short s0 = f2bf(accS[m][0]);
                    short s1 = f2bf(accS[m][1]);
                    short s2 = f2bf(accS[m][2]);
                    short s3 = (k0 + 3 < 47) ? f2bf(accS[m][3]) : (short)0;
                    short* ad = base + (size_t)(g*Mi + x)*8 + j;
                    *(unsigned*)(ad)     = pk(s0, s1);
                    *(unsigned*)(ad + 2) = pk(s2, s3);
                }
            }
        }
    }

    if (!final_i){   // zero pad channels 48..63 (g-planes 6,7)
        for (int f = tid; f < 64*8; f += 256){
            int v = f >> 3, gv = v0 + v;
            if (gv < nvox){
                int u = f & 7;
                int c = 48 + u*2;
                int g = c >> 3, j = c & 7;
                int z = gv / (Mi*Mi);
                int rr = gv % (Mi*Mi);
                int y = rr / Mi, x = rr % Mi;
                *(unsigned*)&c64out[(size_t)(z*Mi + y)*Mi*64 + (size_t)(g*Mi + x)*8 + j] = 0;
            }
        }
    }
}

// ---------------------------------------------------------------------------
extern "C" void kernel_launch(void* const* d_in, const int* in_sizes, int n_in,
                              void* d_out, int out_size, void* d_ws, size_t ws_size,
                              hipStream_t stream){
    const float* b    = (const float*)d_in[0];
    const float* AQ   = (const float*)d_in[1];
    const float* w1   = (const float*)d_in[2];
    const float* b1   = (const float*)d_in[3];
    const float* w2   = (const float*)d_in[4];
    const float* b2   = (const float*)d_in[5];
    const float* w3   = (const float*)d_in[6];
    const float* b3   = (const float*)d_in[7];
    const float* dreg = (const float*)d_in[8];
    float* out = (float*)d_out;
    float* ws  = (float*)d_ws;

    const size_t NV48 = (size_t)48*48*48;                 // 110592
    float* Ainv18 = ws;                                    // 336
    float* AQ_Tb  = ws + 336;                              // NV48*48 (rows padded)
    short* hbuf   = (short*)(AQ_Tb + NV48*48);             // 46^3*96
    short* w1bf   = hbuf + (size_t)46*46*46*NHID;          // 4*27*96*64
    short* w2bf   = w1bf + (size_t)4*27*96*64;             // 4*96*96
    short* w3bf   = w2bf + (size_t)4*96*96;                // 4*96*96
    short* Ainvbf = w3bf + (size_t)4*96*96;                // 48*64
    short* Bseq   = Ainvbf + 48*64;                        // 30720
    short* c64A   = Bseq + 30720;                          // NV48*64 + slack
    short* c64B   = c64A + NV48*64 + 32768;

    prep_small<<<45, 256, 0, stream>>>(AQ, dreg, Ainv18, Ainvbf, Bseq,
                                       w1, w1bf, w2, w3, w2bf, w3bf);
    aqtb_mfma<<<(int)(NV48/64), 256, 0, stream>>>(b, Bseq, Ainv18, AQ_Tb, c64A);

    short* ccur = c64A;
    short* cnext = c64B;
    for (int i = 0; i < 4; ++i){
        int Ni = 48 - 2*i;
        int Mi = Ni - 2;
        int nbx = (Mi + 15)/16;
        int nxy = nbx*nbx;
        int nwg1 = nxy*(Mi/2);
        conv1_mfma<<<nwg1, 1024, 0, stream>>>(ccur, w1bf + (size_t)i*27*96*64, b1 + i*96,
                                              hbuf, Ni, Mi, nxy);
        int nv = Mi*Mi*Mi;
        int fin = (i == 3) ? 1 : 0;
        cascade_mfma<<<(nv + 63)/64, 256, 0, stream>>>(
            hbuf, ccur, AQ_Tb, w2bf + (size_t)i*9216, b2 + i*96,
            w3bf + (size_t)i*9216, b3 + i*94, Ainvbf, dreg, cnext, out, Mi, i+1, i, fin);
        short* t = ccur; ccur = cnext; cnext = t;
    }
}